// Round 5
// baseline (398.527 us; speedup 1.0000x reference)
//
#include <hip/hip_runtime.h>
#include <math.h>

#define NN 4096      // nodes = B*S
#define D 256        // DIN == DOUT
#define RR 8
#define LL 4
#define EE 65536
#define BB 8
#define SS 512
#define HH 8
#define MAXDEG 256

typedef short bf16x8 __attribute__((ext_vector_type(8)));
typedef float f32x4 __attribute__((ext_vector_type(4)));

__device__ __forceinline__ unsigned short f2bf(float f) {
  unsigned u = __float_as_uint(f);
  unsigned r = (u + 0x7fffu + ((u >> 16) & 1u)) >> 16;
  return (unsigned short)r;
}
__device__ __forceinline__ float bf2f(unsigned short s) {
  return __uint_as_float(((unsigned)s) << 16);
}

__device__ __forceinline__ void gload16(unsigned short* dst, const unsigned short* src) {
  __builtin_amdgcn_global_load_lds(
      (const __attribute__((address_space(1))) void*)src,
      (__attribute__((address_space(3))) void*)dst, 16, 0, 0);
}

// ---------------- split-bf16 MFMA GEMM, double-buffered, 1 barrier/K-step ----
// C[M,N] = (Ah+Al)[M,K] * (Bh+Bl)[N,K]^T (+bias) -> ELU? -> split bf16 out.
// 3-term: Ah*Bh + Al*Bh + Ah*Bl, fp32 accum. 256 thr = 4 waves (2x2).
template<int BM, int BN, bool ELU_>
__global__ __launch_bounds__(256) void gemm_split(
    const unsigned short* __restrict__ Ah, const unsigned short* __restrict__ Al,
    const unsigned short* __restrict__ Bh, const unsigned short* __restrict__ Bl,
    const float* __restrict__ bias,
    unsigned short* __restrict__ Ch, unsigned short* __restrict__ Cl,
    int M, int N, int K)
{
  constexpr int MF = BM / 32;
  constexpr int NF = BN / 32;
  constexpr int ABUF = BM * 32;      // shorts per A half-tile (hi or lo)
  constexpr int BBUF = BN * 32;
  constexpr int BUFSZ = 2 * ABUF + 2 * BBUF;
  __shared__ unsigned short lds[2 * BUFSZ];

  const int t = threadIdx.x;
  const int lane = t & 63;
  const int w = t >> 6;
  const int wm = w >> 1, wn = w & 1;
  const int rb = blockIdx.y * BM;
  const int cb = blockIdx.x * BN;

  f32x4 acc[MF][NF];
#pragma unroll
  for (int m = 0; m < MF; ++m)
#pragma unroll
    for (int n = 0; n < NF; ++n)
      acc[m][n] = (f32x4){0.f, 0.f, 0.f, 0.f};

  const int srow = t >> 2, sslot = t & 3;
  const unsigned short* gAh = Ah + (size_t)(rb + srow) * K + sslot * 8;
  const unsigned short* gAl = Al + (size_t)(rb + srow) * K + sslot * 8;
  const unsigned short* gBh = Bh + (size_t)(cb + srow) * K + sslot * 8;
  const unsigned short* gBl = Bl + (size_t)(cb + srow) * K + sslot * 8;

  auto stage = [&](int buf, int k0) {
    unsigned short* p = lds + buf * BUFSZ;
#pragma unroll
    for (int i = 0; i < BM / 64; ++i) {
      gload16(p + i * 2048 + t * 8,        gAh + (size_t)i * 64 * K + k0);
      gload16(p + ABUF + i * 2048 + t * 8, gAl + (size_t)i * 64 * K + k0);
    }
#pragma unroll
    for (int i = 0; i < BN / 64; ++i) {
      gload16(p + 2 * ABUF + i * 2048 + t * 8,        gBh + (size_t)i * 64 * K + k0);
      gload16(p + 2 * ABUF + BBUF + i * 2048 + t * 8, gBl + (size_t)i * 64 * K + k0);
    }
  };

  stage(0, 0);
  int cur = 0;
  for (int k0 = 0; k0 < K; k0 += 32) {
    __syncthreads();                 // drains vmcnt(0): staged tile visible
    if (k0 + 32 < K) stage(cur ^ 1, k0 + 32);   // prefetch overlaps compute
    const unsigned short* p = lds + cur * BUFSZ;

    bf16x8 ah[MF], al[MF];
#pragma unroll
    for (int m = 0; m < MF; ++m) {
      int off = (wm * (BM / 2) + m * 16 + (lane & 15)) * 32 + (lane >> 4) * 8;
      ah[m] = *(const bf16x8*)(p + off);
      al[m] = *(const bf16x8*)(p + ABUF + off);
    }
#pragma unroll
    for (int n = 0; n < NF; ++n) {
      int boff = (wn * (BN / 2) + n * 16 + (lane & 15)) * 32 + (lane >> 4) * 8;
      bf16x8 bh = *(const bf16x8*)(p + 2 * ABUF + boff);
      bf16x8 bl = *(const bf16x8*)(p + 2 * ABUF + BBUF + boff);
#pragma unroll
      for (int m = 0; m < MF; ++m) {
        acc[m][n] = __builtin_amdgcn_mfma_f32_16x16x32_bf16(ah[m], bh, acc[m][n], 0, 0, 0);
        acc[m][n] = __builtin_amdgcn_mfma_f32_16x16x32_bf16(al[m], bh, acc[m][n], 0, 0, 0);
        acc[m][n] = __builtin_amdgcn_mfma_f32_16x16x32_bf16(ah[m], bl, acc[m][n], 0, 0, 0);
      }
    }
    cur ^= 1;
  }

#pragma unroll
  for (int m = 0; m < MF; ++m) {
#pragma unroll
    for (int n = 0; n < NF; ++n) {
      int row0 = rb + wm * (BM / 2) + m * 16 + (lane >> 4) * 4;
      int col = cb + wn * (BN / 2) + n * 16 + (lane & 15);
      float bv = bias ? bias[col] : 0.f;
#pragma unroll
      for (int j = 0; j < 4; ++j) {
        float v = acc[m][n][j] + bv;
        if (ELU_) v = v > 0.f ? v : expm1f(v);
        size_t idx = (size_t)(row0 + j) * N + col;
        unsigned short hb = f2bf(v);
        Ch[idx] = hb;
        Cl[idx] = f2bf(v - bf2f(hb));
      }
    }
  }
}

// ---------------- fp32 -> bf16 hi/lo split ----------------
__global__ __launch_bounds__(256) void cvt_split_k(const float* __restrict__ src,
    unsigned short* __restrict__ hi, unsigned short* __restrict__ lo, int n4)
{
  int i = blockIdx.x * 256 + threadIdx.x;
  if (i >= n4) return;
  float4 v = ((const float4*)src)[i];
  ushort4 h, l;
  h.x = f2bf(v.x); l.x = f2bf(v.x - bf2f(h.x));
  h.y = f2bf(v.y); l.y = f2bf(v.y - bf2f(h.y));
  h.z = f2bf(v.z); l.z = f2bf(v.z - bf2f(h.z));
  h.w = f2bf(v.w); l.w = f2bf(v.w - bf2f(h.w));
  ((ushort4*)hi)[i] = h;
  ((ushort4*)lo)[i] = l;
}

// --- Wgat [l][r][d][e] -> stacked-transposed split Wgt2[l][e][r][d] ----------
__global__ __launch_bounds__(256) void transp2_k(const float* __restrict__ W,
    unsigned short* __restrict__ th, unsigned short* __restrict__ tl)
{
  __shared__ float s[32][33];
  int g = blockIdx.z, bi = blockIdx.y, bj = blockIdx.x;   // g = l*8+r
  int l = g >> 3, r = g & 7;
  int t = threadIdx.x;
  int rr = t >> 3, c = (t & 7) * 4;
  // load tile: rows = d (bi*32+rr), cols = e (bj*32 + c..c+3)
  float4 v = *(const float4*)(W + ((size_t)g * D + bi * 32 + rr) * D + bj * 32 + c);
  s[rr][c + 0] = v.x; s[rr][c + 1] = v.y; s[rr][c + 2] = v.z; s[rr][c + 3] = v.w;
  __syncthreads();
  // write: e = bj*32+rr, d = bi*32 + c..c+3 at [((l*256+e)*8 + r)*256 + d]
  int e = bj * 32 + rr;
  size_t ob = (((size_t)l * 256 + e) * RR + r) * D + bi * 32 + c;
  float o0 = s[c + 0][rr], o1 = s[c + 1][rr], o2 = s[c + 2][rr], o3 = s[c + 3][rr];
  ushort4 h, l4;
  h.x = f2bf(o0); l4.x = f2bf(o0 - bf2f(h.x));
  h.y = f2bf(o1); l4.y = f2bf(o1 - bf2f(h.y));
  h.z = f2bf(o2); l4.z = f2bf(o2 - bf2f(h.z));
  h.w = f2bf(o3); l4.w = f2bf(o3 - bf2f(h.w));
  *(ushort4*)(th + ob) = h;
  *(ushort4*)(tl + ob) = l4;
}

// ---------------- CSR build, keyed by (dst, relation) ----------------
__global__ void count2_k(const int* __restrict__ ed, const int* __restrict__ et,
                         int* __restrict__ cnt) {
  int e = blockIdx.x * 256 + threadIdx.x;
  if (e < EE) atomicAdd(&cnt[ed[e] * RR + et[e]], 1);
}

__global__ __launch_bounds__(1024) void scan2_k(const int* __restrict__ cnt,
    int* __restrict__ off, int* __restrict__ cur) {
  __shared__ int part[1024];
  int t = threadIdx.x;
  int base = t * 32;                      // 32768 counters / 1024 threads
  int s = 0;
  for (int i = 0; i < 32; ++i) s += cnt[base + i];
  part[t] = s;
  __syncthreads();
  for (int o = 1; o < 1024; o <<= 1) {
    int v = 0;
    if (t >= o) v = part[t - o];
    __syncthreads();
    part[t] += v;
    __syncthreads();
  }
  int run = part[t] - s;
  for (int i = 0; i < 32; ++i) {
    off[base + i] = run;
    cur[base + i] = run;
    run += cnt[base + i];
  }
  if (t == 1023) off[NN * RR] = EE;
}

__global__ void fill2_k(const int* __restrict__ ed, const int* __restrict__ et,
                        int* __restrict__ cur, int* __restrict__ csr) {
  int e = blockIdx.x * 256 + threadIdx.x;
  if (e < EE) { int p = atomicAdd(&cur[ed[e] * RR + et[e]], 1); csr[p] = e; }
}

// ------- wa[l,r,d] = sum_e Wgat[l,r,d,e] * a_src[l,r,e]  (all layers) -------
__global__ __launch_bounds__(256) void wa_all_k(const float* __restrict__ Wg,
    const float* __restrict__ asrc, float* __restrict__ wa)
{
  int wid = blockIdx.x * 4 + (threadIdx.x >> 6);   // 0..LL*RR*D-1
  int lane = threadIdx.x & 63;
  int lr = wid >> 8, d = wid & 255;
  const float* row = Wg + ((size_t)lr * D + d) * D;
  const float* av = asrc + (size_t)lr * D;
  float s = 0.f;
  for (int i = lane; i < D; i += 64) s += row[i] * av[i];
#pragma unroll
  for (int o = 32; o; o >>= 1) s += __shfl_down(s, o);
  if (lane == 0) wa[wid] = s;
}

// ------- fold: wqk1[i][k] = sum_j Wsel[i][j] * W1[j][k]  (i<256: Wq else Wk) --
__global__ __launch_bounds__(256) void fold_k(const float* __restrict__ Wq,
    const float* __restrict__ Wk, const float* __restrict__ W1,
    unsigned short* __restrict__ fh, unsigned short* __restrict__ fl)
{
  int j = (blockIdx.x & 3) * 64 + (threadIdx.x & 63);
  int i = (blockIdx.x >> 2) * 4 + (threadIdx.x >> 6);
  const float* row = i < 256 ? Wq + (size_t)i * D : Wk + (size_t)(i - 256) * D;
  float s = 0.f;
  for (int k = 0; k < D; ++k) s += row[k] * W1[(size_t)k * D + j];
  size_t idx = (size_t)i * D + j;
  unsigned short hb = f2bf(s);
  fh[idx] = hb;
  fl[idx] = f2bf(s - bf2f(hb));
}

__global__ __launch_bounds__(256) void foldb_k(const float* __restrict__ Wq,
    const float* __restrict__ Wk, const float* __restrict__ b1,
    const float* __restrict__ bq, const float* __restrict__ bk,
    float* __restrict__ bqk)
{
  int idx = blockIdx.x * 4 + (threadIdx.x >> 6);
  int lane = threadIdx.x & 63;
  const float* row = idx < 256 ? Wq + (size_t)idx * D : Wk + (size_t)(idx - 256) * D;
  float s = 0.f;
  for (int i = lane; i < D; i += 64) s += row[i] * b1[i];
#pragma unroll
  for (int o = 32; o; o >>= 1) s += __shfl_down(s, o);
  if (lane == 0) bqk[idx] = s + (idx < 256 ? bq[idx] : bk[idx - 256]);
}

// ---- scores from split h: ssrc[r,n]=h[n].wa[r], sdst[r,n]=h[n].adst[r] ------
__global__ __launch_bounds__(256) void scores_split_k(
    const unsigned short* __restrict__ hh, const unsigned short* __restrict__ hl,
    const float* __restrict__ wa_l, const float* __restrict__ adst_l,
    float* __restrict__ ssrc, float* __restrict__ sdst)
{
  __shared__ float sh[256];
  int n = blockIdx.x, tid = threadIdx.x;
  size_t idx = (size_t)n * D + tid;
  sh[tid] = bf2f(hh[idx]) + bf2f(hl[idx]);
  __syncthreads();
  int wv = tid >> 6, lane = tid & 63;
#pragma unroll
  for (int rr = 0; rr < 2; ++rr) {
    int r = wv * 2 + rr;
    const float* wr = wa_l + (size_t)r * D;
    const float* ar = adst_l + (size_t)r * D;
    float s1 = sh[lane] * wr[lane] + sh[lane+64] * wr[lane+64]
             + sh[lane+128] * wr[lane+128] + sh[lane+192] * wr[lane+192];
    float s2 = sh[lane] * ar[lane] + sh[lane+64] * ar[lane+64]
             + sh[lane+128] * ar[lane+128] + sh[lane+192] * ar[lane+192];
#pragma unroll
    for (int o = 32; o; o >>= 1) { s1 += __shfl_down(s1, o); s2 += __shfl_down(s2, o); }
    if (lane == 0) { ssrc[(size_t)r * NN + n] = s1; sdst[(size_t)r * NN + n] = s2; }
  }
}

// ---- gather: per node softmax over edges + alpha-weighted gather-sum of h ----
// g[n, r*D+d] = sum_{e into n, type r} alpha_e * h[src_e, d]   (split bf16 out)
__global__ __launch_bounds__(256) void gather_k(
    const int* __restrict__ csr, const int* __restrict__ off2,
    const int* __restrict__ es,
    const float* __restrict__ ssrc, const float* __restrict__ sdst,
    const unsigned short* __restrict__ hh, const unsigned short* __restrict__ hl,
    unsigned short* __restrict__ gh, unsigned short* __restrict__ gl)
{
  __shared__ float sal[MAXDEG];
  __shared__ int ssid[MAXDEG];
  __shared__ int sbnd[RR + 1];
  __shared__ float red[8];
  int n = blockIdx.x, tid = threadIdx.x;
  if (tid <= RR) sbnd[tid] = off2[n * RR + tid];
  __syncthreads();
  int e0 = sbnd[0];
  int deg = sbnd[RR] - e0; if (deg > MAXDEG) deg = MAXDEG;
  // logits (leaky relu) per relation group
  for (int r = 0; r < RR; ++r) {
    float sd = sdst[(size_t)r * NN + n];
    int a = sbnd[r] - e0, b = sbnd[r + 1] - e0;
    if (b > MAXDEG) b = MAXDEG;
    for (int i = a + tid; i < b; i += 256) {
      int e = csr[e0 + i];
      int s = es[e];
      float v = ssrc[(size_t)r * NN + s] + sd;
      sal[i] = v > 0.f ? v : 0.2f * v;
      ssid[i] = s;
    }
  }
  __syncthreads();
  int lane = tid & 63, wv = tid >> 6;
  float lm = -INFINITY;
  for (int i = tid; i < deg; i += 256) lm = fmaxf(lm, sal[i]);
#pragma unroll
  for (int o = 32; o; o >>= 1) lm = fmaxf(lm, __shfl_xor(lm, o));
  if (lane == 0) red[wv] = lm;
  __syncthreads();
  float m = fmaxf(fmaxf(red[0], red[1]), fmaxf(red[2], red[3]));
  float ls = 0.f;
  for (int i = tid; i < deg; i += 256) {
    float a = expf(sal[i] - m);
    sal[i] = a;
    ls += a;
  }
#pragma unroll
  for (int o = 32; o; o >>= 1) ls += __shfl_xor(ls, o);
  if (lane == 0) red[4 + wv] = ls;
  __syncthreads();
  float dinv = 1.f / (red[4] + red[5] + red[6] + red[7] + 1e-16f);
  // aggregate: thread = channel d; one accumulator per relation group
  for (int r = 0; r < RR; ++r) {
    int a = sbnd[r] - e0, b = sbnd[r + 1] - e0;
    if (b > MAXDEG) b = MAXDEG;
    float acc = 0.f;
    for (int i = a; i < b; ++i) {
      int s = ssid[i];
      float hv = bf2f(hh[(size_t)s * D + tid]) + bf2f(hl[(size_t)s * D + tid]);
      acc += sal[i] * hv;
    }
    acc *= dinv;
    size_t idx = (size_t)n * (RR * D) + r * D + tid;
    unsigned short hb = f2bf(acc);
    gh[idx] = hb;
    gl[idx] = f2bf(acc - bf2f(hb));
  }
}

// ---------------- final attention scores via split-bf16 MFMA ----------------
// qk layout: [NN][512] hi/lo; q = cols [0,256), k = cols [256,512)
__global__ __launch_bounds__(256) void attn_mfma_k(
    const unsigned short* __restrict__ qkh, const unsigned short* __restrict__ qkl,
    float* __restrict__ out)
{
  int bh = blockIdx.y; int b = bh >> 3, hd = bh & 7;
  int rb = (blockIdx.x >> 3) * 64, cb = (blockIdx.x & 7) * 64;
  int t = threadIdx.x, lane = t & 63, w = t >> 6;
  int wm = w >> 1, wn = w & 1;
  int colq = hd * 32 + (lane >> 4) * 8;
  int colk = 256 + colq;
  int arow = b * SS + rb + wm * 32 + (lane & 15);
  int brow = b * SS + cb + wn * 32 + (lane & 15);

  bf16x8 aH[2], aL[2], bH[2], bL[2];
#pragma unroll
  for (int m = 0; m < 2; ++m) {
    size_t o1 = (size_t)(arow + m * 16) * 512 + colq;
    aH[m] = *(const bf16x8*)(qkh + o1);
    aL[m] = *(const bf16x8*)(qkl + o1);
    size_t o2 = (size_t)(brow + m * 16) * 512 + colk;
    bH[m] = *(const bf16x8*)(qkh + o2);
    bL[m] = *(const bf16x8*)(qkl + o2);
  }
  f32x4 acc[2][2];
#pragma unroll
  for (int m = 0; m < 2; ++m)
#pragma unroll
    for (int n = 0; n < 2; ++n) {
      acc[m][n] = (f32x4){0.f, 0.f, 0.f, 0.f};
      acc[m][n] = __builtin_amdgcn_mfma_f32_16x16x32_bf16(aH[m], bH[n], acc[m][n], 0, 0, 0);
      acc[m][n] = __builtin_amdgcn_mfma_f32_16x16x32_bf16(aL[m], bH[n], acc[m][n], 0, 0, 0);
      acc[m][n] = __builtin_amdgcn_mfma_f32_16x16x32_bf16(aH[m], bL[n], acc[m][n], 0, 0, 0);
    }
  const float scale = 0.17677669529663687f; // 1/sqrt(32)
  size_t ob = (size_t)bh * SS * SS;
#pragma unroll
  for (int m = 0; m < 2; ++m)
#pragma unroll
    for (int n = 0; n < 2; ++n) {
      int row0 = rb + wm * 32 + m * 16 + (lane >> 4) * 4;
      int col = cb + wn * 32 + n * 16 + (lane & 15);
#pragma unroll
      for (int j = 0; j < 4; ++j)
        out[ob + (size_t)(row0 + j) * SS + col] = acc[m][n][j] * scale;
    }
}

// ---------------- launcher ----------------
extern "C" void kernel_launch(void* const* d_in, const int* in_sizes, int n_in,
                              void* d_out, int out_size, void* d_ws, size_t ws_size,
                              hipStream_t stream) {
  const float* x    = (const float*)d_in[0];
  const int*   es   = (const int*)d_in[1];
  const int*   ed   = (const int*)d_in[2];
  const int*   et   = (const int*)d_in[3];
  const float* Wl   = (const float*)d_in[4];
  const float* bl   = (const float*)d_in[5];
  const float* Wgat = (const float*)d_in[6];
  const float* asr  = (const float*)d_in[7];
  const float* adt  = (const float*)d_in[8];
  const float* W1   = (const float*)d_in[9];
  const float* b1   = (const float*)d_in[10];
  const float* Wq   = (const float*)d_in[11];
  const float* bq   = (const float*)d_in[12];
  const float* Wk   = (const float*)d_in[13];
  const float* bk   = (const float*)d_in[14];
  float* out = (float*)d_out;

  char* w = (char*)d_ws;
  size_t o = 0;
  auto alloc = [&](size_t bytes) { void* p = w + o; o += (bytes + 255) & ~(size_t)255; return p; };
  unsigned short* hh    = (unsigned short*)alloc((size_t)NN * D * 2);
  unsigned short* hl    = (unsigned short*)alloc((size_t)NN * D * 2);
  unsigned short* Wgt2h = (unsigned short*)alloc((size_t)LL * RR * D * D * 2);
  unsigned short* Wgt2l = (unsigned short*)alloc((size_t)LL * RR * D * D * 2);
  unsigned short* wlh   = (unsigned short*)alloc((size_t)D * D * 2);
  unsigned short* wll   = (unsigned short*)alloc((size_t)D * D * 2);
  unsigned short* fqkh  = (unsigned short*)alloc((size_t)2 * D * D * 2);
  unsigned short* fqkl  = (unsigned short*)alloc((size_t)2 * D * D * 2);
  float* bqk   = (float*)alloc((size_t)2 * D * 4);
  float* wa    = (float*)alloc((size_t)LL * RR * D * 4);
  float* ssrc  = (float*)alloc((size_t)RR * NN * 4);
  float* sdst  = (float*)alloc((size_t)RR * NN * 4);
  int*   cnt2  = (int*)alloc((size_t)NN * RR * 4);
  int*   off2  = (int*)alloc((size_t)(NN * RR + 1) * 4);
  int*   cur2  = (int*)alloc((size_t)NN * RR * 4);
  int*   csr   = (int*)alloc((size_t)EE * 4);
  // 32 MB multipurpose region
  char* big = (char*)alloc((size_t)NN * RR * D * 4);
  unsigned short* xh  = (unsigned short*)big;                       // before layers
  unsigned short* xl  = (unsigned short*)(big + (size_t)NN * D * 2);
  unsigned short* gh  = (unsigned short*)big;                       // [NN][2048] hi
  unsigned short* gl  = (unsigned short*)(big + (size_t)NN * RR * D * 2);  // lo
  unsigned short* qkh = (unsigned short*)big;                       // after layers
  unsigned short* qkl = (unsigned short*)(big + (size_t)NN * 512 * 2);

  // CSR build, keyed by (dst, rel)
  hipMemsetAsync(cnt2, 0, NN * RR * sizeof(int), stream);
  count2_k<<<EE / 256, 256, 0, stream>>>(ed, et, cnt2);
  scan2_k<<<1, 1024, 0, stream>>>(cnt2, off2, cur2);
  fill2_k<<<EE / 256, 256, 0, stream>>>(ed, et, cur2, csr);

  // conversions + precomputation
  cvt_split_k<<<NN * D / 1024, 256, 0, stream>>>(x, xh, xl, NN * D / 4);
  cvt_split_k<<<D * D / 1024, 256, 0, stream>>>(Wl, wlh, wll, D * D / 4);
  transp2_k<<<dim3(8, 8, LL * RR), 256, 0, stream>>>(Wgat, Wgt2h, Wgt2l);
  wa_all_k<<<LL * RR * D / 4, 256, 0, stream>>>(Wgat, asr, wa);
  fold_k<<<512, 256, 0, stream>>>(Wq, Wk, W1, fqkh, fqkl);
  foldb_k<<<128, 256, 0, stream>>>(Wq, Wk, b1, bq, bk, bqk);

  // h = x @ Wl^T + bl  (split out)
  gemm_split<64, 64, false><<<dim3(4, 64), 256, 0, stream>>>(
      xh, xl, wlh, wll, bl, hh, hl, NN, D, D);
  scores_split_k<<<NN, 256, 0, stream>>>(hh, hl, wa, adt, ssrc, sdst);

  for (int l = 0; l < LL; ++l) {
    // g[n, r*D+d] = sum alpha * h_src  (aggregate first...)
    gather_k<<<NN, 256, 0, stream>>>(csr, off2, es, ssrc, sdst, hh, hl, gh, gl);
    // ...then transform: h' = ELU( g @ Wstack ), M=4096 N=256 K=2048
    gemm_split<64, 64, true><<<dim3(4, 64), 256, 0, stream>>>(
        gh, gl, Wgt2h + (size_t)l * RR * D * D, Wgt2l + (size_t)l * RR * D * D,
        nullptr, hh, hl, NN, D, RR * D);
    if (l < LL - 1)
      scores_split_k<<<NN, 256, 0, stream>>>(hh, hl, wa + (size_t)(l + 1) * RR * D,
                                             adt + (size_t)(l + 1) * RR * D, ssrc, sdst);
  }

  // [q|k] = h @ (W{q,k}·W1)^T + (W{q,k}·b1 + b{q,k})   — one GEMM, N=512
  gemm_split<64, 64, false><<<dim3(8, 64), 256, 0, stream>>>(
      hh, hl, fqkh, fqkl, bqk, qkh, qkl, NN, 512, D);

  attn_mfma_k<<<dim3(64, BB * HH), 256, 0, stream>>>(qkh, qkl, out);
}

// Round 6
// 249.645 us; speedup vs baseline: 1.5964x; 1.5964x over previous
//
#include <hip/hip_runtime.h>
#include <math.h>

#define NN 4096      // nodes = B*S
#define D 256        // DIN == DOUT
#define RR 8
#define LL 4
#define EE 65536
#define BB 8
#define SS 512
#define HH 8

typedef short bf16x8 __attribute__((ext_vector_type(8)));
typedef float f32x4 __attribute__((ext_vector_type(4)));

__device__ __forceinline__ unsigned short f2bf(float f) {
  unsigned u = __float_as_uint(f);
  unsigned r = (u + 0x7fffu + ((u >> 16) & 1u)) >> 16;
  return (unsigned short)r;
}
__device__ __forceinline__ float bf2f(unsigned short s) {
  return __uint_as_float(((unsigned)s) << 16);
}

__device__ __forceinline__ void gload16(unsigned short* dst, const unsigned short* src) {
  __builtin_amdgcn_global_load_lds(
      (const __attribute__((address_space(1))) void*)src,
      (__attribute__((address_space(3))) void*)dst, 16, 0, 0);
}

// ---------------- split-bf16 MFMA GEMM ----------------
// C[M,N] = (Ah+Al)[M,K] * (Bh+Bl)[N,K]^T (+bias), fp32 accum.
// 3-term split: Ah*Bh + Al*Bh + Ah*Bl. 256 threads = 4 waves (2x2).
// Double-buffered LDS, ONE barrier per K-step (barrier's implicit vmcnt(0)
// drain publishes the staged tile). k-slot XOR-swizzle (slot ^= (row>>1)&3)
// applied on BOTH the global source (LDS dest linear, rule #21) and ds_read
// to turn the 8-way row-column bank conflict into a free 2-way.
template<int BM, int BN, bool F32OUT, bool SPLITOUT>
__global__ __launch_bounds__(256) void gemm_split(
    const unsigned short* __restrict__ Ah, const unsigned short* __restrict__ Al,
    const unsigned short* __restrict__ Bh, const unsigned short* __restrict__ Bl,
    const float* __restrict__ bias,
    float* __restrict__ C, unsigned short* __restrict__ Ch, unsigned short* __restrict__ Cl,
    int M, int N, int K)
{
  constexpr int MF = BM / 32;
  constexpr int NF = BN / 32;
  constexpr int ABUF = BM * 32;      // shorts per A half-tile (hi or lo)
  constexpr int BBUF = BN * 32;
  constexpr int BUFSZ = 2 * ABUF + 2 * BBUF;
  __shared__ unsigned short lds[2 * BUFSZ];

  const int t = threadIdx.x;
  const int lane = t & 63;
  const int w = t >> 6;
  const int wm = w >> 1, wn = w & 1;
  const int rb = blockIdx.y * BM;
  const int cb = blockIdx.x * BN;

  f32x4 acc[MF][NF];
#pragma unroll
  for (int m = 0; m < MF; ++m)
#pragma unroll
    for (int n = 0; n < NF; ++n)
      acc[m][n] = (f32x4){0.f, 0.f, 0.f, 0.f};

  const int srow = t >> 2;
  const int lslot = (t & 3) ^ ((srow >> 1) & 3);    // pre-swizzled source slot
  const unsigned short* gAh = Ah + (size_t)(rb + srow) * K + lslot * 8;
  const unsigned short* gAl = Al + (size_t)(rb + srow) * K + lslot * 8;
  const unsigned short* gBh = Bh + (size_t)(cb + srow) * K + lslot * 8;
  const unsigned short* gBl = Bl + (size_t)(cb + srow) * K + lslot * 8;

  auto stage = [&](int buf, int k0) {
    unsigned short* p = lds + buf * BUFSZ;
#pragma unroll
    for (int i = 0; i < BM / 64; ++i) {
      gload16(p + i * 2048 + t * 8,        gAh + (size_t)i * 64 * K + k0);
      gload16(p + ABUF + i * 2048 + t * 8, gAl + (size_t)i * 64 * K + k0);
    }
#pragma unroll
    for (int i = 0; i < BN / 64; ++i) {
      gload16(p + 2 * ABUF + i * 2048 + t * 8,        gBh + (size_t)i * 64 * K + k0);
      gload16(p + 2 * ABUF + BBUF + i * 2048 + t * 8, gBl + (size_t)i * 64 * K + k0);
    }
  };

  stage(0, 0);
  int cur = 0;
  for (int k0 = 0; k0 < K; k0 += 32) {
    __syncthreads();                         // drains vmcnt(0): tile visible
    if (k0 + 32 < K) stage(cur ^ 1, k0 + 32);  // prefetch overlaps compute
    const unsigned short* p = lds + cur * BUFSZ;

    bf16x8 ah[MF], al[MF];
#pragma unroll
    for (int m = 0; m < MF; ++m) {
      int row = wm * (BM / 2) + m * 16 + (lane & 15);
      int off = row * 32 + (((lane >> 4) ^ ((row >> 1) & 3)) << 3);
      ah[m] = *(const bf16x8*)(p + off);
      al[m] = *(const bf16x8*)(p + ABUF + off);
    }
#pragma unroll
    for (int n = 0; n < NF; ++n) {
      int brow = wn * (BN / 2) + n * 16 + (lane & 15);
      int boff = brow * 32 + (((lane >> 4) ^ ((brow >> 1) & 3)) << 3);
      bf16x8 bh = *(const bf16x8*)(p + 2 * ABUF + boff);
      bf16x8 bl = *(const bf16x8*)(p + 2 * ABUF + BBUF + boff);
#pragma unroll
      for (int m = 0; m < MF; ++m) {
        acc[m][n] = __builtin_amdgcn_mfma_f32_16x16x32_bf16(ah[m], bh, acc[m][n], 0, 0, 0);
        acc[m][n] = __builtin_amdgcn_mfma_f32_16x16x32_bf16(al[m], bh, acc[m][n], 0, 0, 0);
        acc[m][n] = __builtin_amdgcn_mfma_f32_16x16x32_bf16(ah[m], bl, acc[m][n], 0, 0, 0);
      }
    }
    cur ^= 1;
  }

#pragma unroll
  for (int m = 0; m < MF; ++m) {
#pragma unroll
    for (int n = 0; n < NF; ++n) {
      int row0 = rb + wm * (BM / 2) + m * 16 + (lane >> 4) * 4;
      int col = cb + wn * (BN / 2) + n * 16 + (lane & 15);
      float bv = bias ? bias[col] : 0.f;
#pragma unroll
      for (int j = 0; j < 4; ++j) {
        float v = acc[m][n][j] + bv;
        size_t idx = (size_t)(row0 + j) * N + col;
        if (F32OUT) C[idx] = v;
        if (SPLITOUT) {
          unsigned short hb = f2bf(v);
          Ch[idx] = hb;
          Cl[idx] = f2bf(v - bf2f(hb));
        }
      }
    }
  }
}

// ---------------- fp32 -> bf16 hi/lo split ----------------
__global__ __launch_bounds__(256) void cvt_split_k(const float* __restrict__ src,
    unsigned short* __restrict__ hi, unsigned short* __restrict__ lo, int n4)
{
  int i = blockIdx.x * 256 + threadIdx.x;
  if (i >= n4) return;
  float4 v = ((const float4*)src)[i];
  ushort4 h, l;
  h.x = f2bf(v.x); l.x = f2bf(v.x - bf2f(h.x));
  h.y = f2bf(v.y); l.y = f2bf(v.y - bf2f(h.y));
  h.z = f2bf(v.z); l.z = f2bf(v.z - bf2f(h.z));
  h.w = f2bf(v.w); l.w = f2bf(v.w - bf2f(h.w));
  ((ushort4*)hi)[i] = h;
  ((ushort4*)lo)[i] = l;
}

// ---------------- Wgat [G][D][D] -> transposed hi/lo [G][D][D] (e-major) ---------
__global__ __launch_bounds__(256) void transp_split_k(const float* __restrict__ W,
    unsigned short* __restrict__ th, unsigned short* __restrict__ tl)
{
  __shared__ float s[32][33];
  int g = blockIdx.z, bi = blockIdx.y, bj = blockIdx.x;
  int t = threadIdx.x;
  int r = t >> 3, c = (t & 7) * 4;
  float4 v = *(const float4*)(W + ((size_t)g * D + bi * 32 + r) * D + bj * 32 + c);
  s[r][c + 0] = v.x; s[r][c + 1] = v.y; s[r][c + 2] = v.z; s[r][c + 3] = v.w;
  __syncthreads();
  size_t ob = ((size_t)g * D + bj * 32 + r) * D + bi * 32 + c;
  ushort4 h, l;
  float o0 = s[c + 0][r], o1 = s[c + 1][r], o2 = s[c + 2][r], o3 = s[c + 3][r];
  h.x = f2bf(o0); l.x = f2bf(o0 - bf2f(h.x));
  h.y = f2bf(o1); l.y = f2bf(o1 - bf2f(h.y));
  h.z = f2bf(o2); l.z = f2bf(o2 - bf2f(h.z));
  h.w = f2bf(o3); l.w = f2bf(o3 - bf2f(h.w));
  *(ushort4*)(th + ob) = h;
  *(ushort4*)(tl + ob) = l;
}

// ---------------- CSR build ----------------
__global__ void count_k(const int* __restrict__ ed, int* __restrict__ cnt) {
  int e = blockIdx.x * 256 + threadIdx.x;
  if (e < EE) atomicAdd(&cnt[ed[e]], 1);
}

__global__ __launch_bounds__(1024) void scan_k(const int* __restrict__ cnt,
    int* __restrict__ off, int* __restrict__ cur) {
  __shared__ int part[1024];
  int t = threadIdx.x;
  int base = t * 4;
  int c0 = cnt[base], c1 = cnt[base+1], c2 = cnt[base+2], c3 = cnt[base+3];
  int s = c0 + c1 + c2 + c3;
  part[t] = s;
  __syncthreads();
  for (int o = 1; o < 1024; o <<= 1) {
    int v = 0;
    if (t >= o) v = part[t - o];
    __syncthreads();
    part[t] += v;
    __syncthreads();
  }
  int excl = part[t] - s;
  off[base] = excl; off[base+1] = excl + c0; off[base+2] = excl + c0 + c1;
  off[base+3] = excl + c0 + c1 + c2;
  cur[base] = excl; cur[base+1] = excl + c0; cur[base+2] = excl + c0 + c1;
  cur[base+3] = excl + c0 + c1 + c2;
  if (t == 1023) off[NN] = EE;
}

__global__ void fill_k(const int* __restrict__ ed, int* __restrict__ cur,
                       int* __restrict__ csr) {
  int e = blockIdx.x * 256 + threadIdx.x;
  if (e < EE) { int p = atomicAdd(&cur[ed[e]], 1); csr[p] = e; }
}

// ------- wa[l,r,d] = sum_e Wgat[l,r,d,e] * a_src[l,r,e]  (all layers) -------
__global__ __launch_bounds__(256) void wa_all_k(const float* __restrict__ Wg,
    const float* __restrict__ asrc, float* __restrict__ wa)
{
  int wid = blockIdx.x * 4 + (threadIdx.x >> 6);   // 0..LL*RR*D-1
  int lane = threadIdx.x & 63;
  int lr = wid >> 8, d = wid & 255;                // lr = l*RR + r
  const float* row = Wg + ((size_t)lr * D + d) * D;
  const float* av = asrc + (size_t)lr * D;
  float s = 0.f;
  for (int i = lane; i < D; i += 64) s += row[i] * av[i];
#pragma unroll
  for (int o = 32; o; o >>= 1) s += __shfl_down(s, o);
  if (lane == 0) wa[wid] = s;
}

// ------- fold: wqk1[i][k] = sum_j Wsel[i][j] * W1[j][k]  (i<256: Wq, else Wk) ----
__global__ __launch_bounds__(256) void fold_k(const float* __restrict__ Wq,
    const float* __restrict__ Wk, const float* __restrict__ W1,
    unsigned short* __restrict__ fh, unsigned short* __restrict__ fl)
{
  int j = (blockIdx.x & 3) * 64 + (threadIdx.x & 63);   // output k index 0..255
  int i = (blockIdx.x >> 2) * 4 + (threadIdx.x >> 6);   // output row 0..511
  const float* row = i < 256 ? Wq + (size_t)i * D : Wk + (size_t)(i - 256) * D;
  float s = 0.f;
  for (int k = 0; k < D; ++k) s += row[k] * W1[(size_t)k * D + j];
  size_t idx = (size_t)i * D + j;
  unsigned short hb = f2bf(s);
  fh[idx] = hb;
  fl[idx] = f2bf(s - bf2f(hb));
}

// ------- fold bias: bqk[i] = Wsel[i] . b1 + bsel[i] ----------------
__global__ __launch_bounds__(256) void foldb_k(const float* __restrict__ Wq,
    const float* __restrict__ Wk, const float* __restrict__ b1,
    const float* __restrict__ bq, const float* __restrict__ bk,
    float* __restrict__ bqk)
{
  int idx = blockIdx.x * 4 + (threadIdx.x >> 6);  // 0..511
  int lane = threadIdx.x & 63;
  const float* row = idx < 256 ? Wq + (size_t)idx * D : Wk + (size_t)(idx - 256) * D;
  float s = 0.f;
  for (int i = lane; i < D; i += 64) s += row[i] * b1[i];
#pragma unroll
  for (int o = 32; o; o >>= 1) s += __shfl_down(s, o);
  if (lane == 0) bqk[idx] = s + (idx < 256 ? bq[idx] : bk[idx - 256]);
}

// ---------------- layer-0 scores: ssrc[r,n]=h[n].wa[r], sdst[r,n]=h[n].adst[r] ----
__global__ __launch_bounds__(256) void scores2_k(const float* __restrict__ h,
    const float* __restrict__ wa, const float* __restrict__ adst,
    float* __restrict__ ssrc, float* __restrict__ sdst)
{
  int n = blockIdx.x;
  int w = threadIdx.x >> 6, lane = threadIdx.x & 63;
  float4 hv = ((const float4*)(h + (size_t)n * D))[lane];
#pragma unroll
  for (int rr = 0; rr < 2; ++rr) {
    int r = w * 2 + rr;
    float4 a = ((const float4*)(wa + (size_t)r * D))[lane];
    float4 b = ((const float4*)(adst + (size_t)r * D))[lane];
    float s1 = hv.x*a.x + hv.y*a.y + hv.z*a.z + hv.w*a.w;
    float s2 = hv.x*b.x + hv.y*b.y + hv.z*b.z + hv.w*b.w;
#pragma unroll
    for (int o = 32; o; o >>= 1) { s1 += __shfl_down(s1, o); s2 += __shfl_down(s2, o); }
    if (lane == 0) { ssrc[(size_t)r * NN + n] = s1; sdst[(size_t)r * NN + n] = s2; }
  }
}

// ---- fully fused per-node: logits + softmax + aggregate + ELU + split +
// ---- next-layer scores. One block (256 thr) per node.
__global__ __launch_bounds__(256) void agg_fused_k(
    const int* __restrict__ csr, const int* __restrict__ off,
    const int* __restrict__ et, const int* __restrict__ es,
    const float* __restrict__ ssrc, const float* __restrict__ sdst,
    const float* __restrict__ hr2,
    unsigned short* __restrict__ hh, unsigned short* __restrict__ hl,
    const float* __restrict__ wa_next, const float* __restrict__ adst_next,
    float* __restrict__ ssrc_o, float* __restrict__ sdst_o)
{
  __shared__ float slog[1024];
  __shared__ int soff[1024];
  __shared__ float sdn[RR];
  __shared__ float red[8];
  int n = blockIdx.x, tid = threadIdx.x;
  int o0 = off[n];
  int deg = off[n + 1] - o0;
  if (deg > 1024) deg = 1024;
  if (tid < RR) sdn[tid] = sdst[(size_t)tid * NN + n];
  __syncthreads();
  // logits (leaky relu) into LDS
  for (int i = tid; i < deg; i += 256) {
    int e = csr[o0 + i];
    int t = et[e], s = es[e];
    float v = ssrc[(size_t)t * NN + s] + sdn[t];
    slog[i] = v > 0.f ? v : 0.2f * v;
    soff[i] = s * (RR * D) + t * D;
  }
  __syncthreads();
  int lane = tid & 63, wv = tid >> 6;
  // block max
  float lm = -INFINITY;
  for (int i = tid; i < deg; i += 256) lm = fmaxf(lm, slog[i]);
#pragma unroll
  for (int o = 32; o; o >>= 1) lm = fmaxf(lm, __shfl_xor(lm, o));
  if (lane == 0) red[wv] = lm;
  __syncthreads();
  float m = fmaxf(fmaxf(red[0], red[1]), fmaxf(red[2], red[3]));
  // exp + block sum
  float ls = 0.f;
  for (int i = tid; i < deg; i += 256) {
    float a = expf(slog[i] - m);
    slog[i] = a;
    ls += a;
  }
#pragma unroll
  for (int o = 32; o; o >>= 1) ls += __shfl_xor(ls, o);
  if (lane == 0) red[4 + wv] = ls;
  __syncthreads();
  float dinv = 1.f / (red[4] + red[5] + red[6] + red[7] + 1e-16f);
  // aggregation: thread = channel
  float acc = 0.f;
  for (int i = 0; i < deg; ++i)
    acc += slog[i] * hr2[(size_t)soff[i] + tid];
  acc *= dinv;
  float v = acc > 0.f ? acc : expm1f(acc);
  size_t idx = (size_t)n * D + tid;
  unsigned short hb = f2bf(v);
  hh[idx] = hb;
  hl[idx] = f2bf(v - bf2f(hb));

  if (wa_next) {   // fused scores for next layer (into ping-pong buffers)
    __syncthreads();
    slog[tid] = v;
    __syncthreads();
#pragma unroll
    for (int rr2 = 0; rr2 < 2; ++rr2) {
      int r = wv * 2 + rr2;
      const float* wr = wa_next + (size_t)r * D;
      const float* ar = adst_next + (size_t)r * D;
      float s1 = slog[lane] * wr[lane] + slog[lane+64] * wr[lane+64]
               + slog[lane+128] * wr[lane+128] + slog[lane+192] * wr[lane+192];
      float s2 = slog[lane] * ar[lane] + slog[lane+64] * ar[lane+64]
               + slog[lane+128] * ar[lane+128] + slog[lane+192] * ar[lane+192];
#pragma unroll
      for (int o = 32; o; o >>= 1) { s1 += __shfl_down(s1, o); s2 += __shfl_down(s2, o); }
      if (lane == 0) { ssrc_o[(size_t)r * NN + n] = s1; sdst_o[(size_t)r * NN + n] = s2; }
    }
  }
}

// ---------------- final attention scores via split-bf16 MFMA ----------------
// qk layout: [NN][512] hi/lo; q = cols [0,256), k = cols [256,512)
__global__ __launch_bounds__(256) void attn_mfma_k(
    const unsigned short* __restrict__ qkh, const unsigned short* __restrict__ qkl,
    float* __restrict__ out)
{
  int bh = blockIdx.y; int b = bh >> 3, hd = bh & 7;
  int rb = (blockIdx.x >> 3) * 64, cb = (blockIdx.x & 7) * 64;
  int t = threadIdx.x, lane = t & 63, w = t >> 6;
  int wm = w >> 1, wn = w & 1;
  int colq = hd * 32 + (lane >> 4) * 8;
  int colk = 256 + colq;
  int arow = b * SS + rb + wm * 32 + (lane & 15);
  int brow = b * SS + cb + wn * 32 + (lane & 15);

  bf16x8 aH[2], aL[2], bH[2], bL[2];
#pragma unroll
  for (int m = 0; m < 2; ++m) {
    size_t o1 = (size_t)(arow + m * 16) * 512 + colq;
    aH[m] = *(const bf16x8*)(qkh + o1);
    aL[m] = *(const bf16x8*)(qkl + o1);
    size_t o2 = (size_t)(brow + m * 16) * 512 + colk;
    bH[m] = *(const bf16x8*)(qkh + o2);
    bL[m] = *(const bf16x8*)(qkl + o2);
  }
  f32x4 acc[2][2];
#pragma unroll
  for (int m = 0; m < 2; ++m)
#pragma unroll
    for (int n = 0; n < 2; ++n) {
      acc[m][n] = (f32x4){0.f, 0.f, 0.f, 0.f};
      acc[m][n] = __builtin_amdgcn_mfma_f32_16x16x32_bf16(aH[m], bH[n], acc[m][n], 0, 0, 0);
      acc[m][n] = __builtin_amdgcn_mfma_f32_16x16x32_bf16(aL[m], bH[n], acc[m][n], 0, 0, 0);
      acc[m][n] = __builtin_amdgcn_mfma_f32_16x16x32_bf16(aH[m], bL[n], acc[m][n], 0, 0, 0);
    }
  const float scale = 0.17677669529663687f; // 1/sqrt(32)
  size_t ob = (size_t)bh * SS * SS;
#pragma unroll
  for (int m = 0; m < 2; ++m)
#pragma unroll
    for (int n = 0; n < 2; ++n) {
      int row0 = rb + wm * 32 + m * 16 + (lane >> 4) * 4;
      int col = cb + wn * 32 + n * 16 + (lane & 15);
#pragma unroll
      for (int j = 0; j < 4; ++j)
        out[ob + (size_t)(row0 + j) * SS + col] = acc[m][n][j] * scale;
    }
}

// ---------------- launcher ----------------
extern "C" void kernel_launch(void* const* d_in, const int* in_sizes, int n_in,
                              void* d_out, int out_size, void* d_ws, size_t ws_size,
                              hipStream_t stream) {
  const float* x    = (const float*)d_in[0];
  const int*   es   = (const int*)d_in[1];
  const int*   ed   = (const int*)d_in[2];
  const int*   et   = (const int*)d_in[3];
  const float* Wl   = (const float*)d_in[4];
  const float* bl   = (const float*)d_in[5];
  const float* Wgat = (const float*)d_in[6];
  const float* asr  = (const float*)d_in[7];
  const float* adt  = (const float*)d_in[8];
  const float* W1   = (const float*)d_in[9];
  const float* b1   = (const float*)d_in[10];
  const float* Wq   = (const float*)d_in[11];
  const float* bq   = (const float*)d_in[12];
  const float* Wk   = (const float*)d_in[13];
  const float* bk   = (const float*)d_in[14];
  float* out = (float*)d_out;

  char* w = (char*)d_ws;
  size_t o = 0;
  auto alloc = [&](size_t bytes) { void* p = w + o; o += (bytes + 255) & ~(size_t)255; return p; };
  float*          h     = (float*)alloc((size_t)NN * D * 4);
  unsigned short* hh    = (unsigned short*)alloc((size_t)NN * D * 2);
  unsigned short* hl    = (unsigned short*)alloc((size_t)NN * D * 2);
  unsigned short* Wgt_h = (unsigned short*)alloc((size_t)LL * RR * D * D * 2);
  unsigned short* Wgt_l = (unsigned short*)alloc((size_t)LL * RR * D * D * 2);
  unsigned short* wlh   = (unsigned short*)alloc((size_t)D * D * 2);
  unsigned short* wll   = (unsigned short*)alloc((size_t)D * D * 2);
  unsigned short* fqkh  = (unsigned short*)alloc((size_t)2 * D * D * 2);   // folded [512][256]
  unsigned short* fqkl  = (unsigned short*)alloc((size_t)2 * D * D * 2);
  float* bqk   = (float*)alloc((size_t)2 * D * 4);
  float* wa    = (float*)alloc((size_t)LL * RR * D * 4);
  float* ssrcA = (float*)alloc((size_t)RR * NN * 4);
  float* sdstA = (float*)alloc((size_t)RR * NN * 4);
  float* ssrcB = (float*)alloc((size_t)RR * NN * 4);
  float* sdstB = (float*)alloc((size_t)RR * NN * 4);
  int*   cnt   = (int*)alloc((size_t)NN * 4);
  int*   off   = (int*)alloc((size_t)(NN + 1) * 4);
  int*   cur   = (int*)alloc((size_t)NN * 4);
  int*   csr   = (int*)alloc((size_t)EE * 4);
  // 32 MB multipurpose region
  char* big = (char*)alloc((size_t)NN * RR * D * 4);
  float*          hr2 = (float*)big;                     // [NN][R*D] during layers
  unsigned short* xh  = (unsigned short*)big;            // before layers
  unsigned short* xl  = (unsigned short*)(big + (size_t)NN * D * 2);
  unsigned short* qkh = (unsigned short*)big;            // after layers [NN][512]
  unsigned short* qkl = (unsigned short*)(big + (size_t)NN * 512 * 2);

  // CSR build
  hipMemsetAsync(cnt, 0, NN * sizeof(int), stream);
  count_k<<<EE / 256, 256, 0, stream>>>(ed, cnt);
  scan_k<<<1, 1024, 0, stream>>>(cnt, off, cur);
  fill_k<<<EE / 256, 256, 0, stream>>>(ed, cur, csr);

  // conversions + precomputation
  cvt_split_k<<<NN * D / 1024, 256, 0, stream>>>(x, xh, xl, NN * D / 4);
  cvt_split_k<<<D * D / 1024, 256, 0, stream>>>(Wl, wlh, wll, D * D / 4);
  transp_split_k<<<dim3(8, 8, LL * RR), 256, 0, stream>>>(Wgat, Wgt_h, Wgt_l);
  wa_all_k<<<LL * RR * D / 4, 256, 0, stream>>>(Wgat, asr, wa);
  fold_k<<<512, 256, 0, stream>>>(Wq, Wk, W1, fqkh, fqkl);
  foldb_k<<<128, 256, 0, stream>>>(Wq, Wk, b1, bq, bk, bqk);

  // h = x @ Wl^T + bl (fp32 for layer-0 scores + split for GEMM)
  gemm_split<64, 64, true, true><<<dim3(4, 64), 256, 0, stream>>>(
      xh, xl, wlh, wll, bl, h, hh, hl, NN, D, D);
  scores2_k<<<NN, 256, 0, stream>>>(h, wa, adt, ssrcA, sdstA);

  for (int l = 0; l < LL; ++l) {
    // hr2[n, r*D+e] = h @ Wgat[l] (fused over relations, N=2048)
    gemm_split<128, 128, true, false><<<dim3(16, 32), 256, 0, stream>>>(
        hh, hl, Wgt_h + (size_t)l * RR * D * D, Wgt_l + (size_t)l * RR * D * D,
        nullptr, hr2, nullptr, nullptr, NN, RR * D, D);
    const float* wan = (l < LL - 1) ? wa + (size_t)(l + 1) * RR * D : nullptr;
    const float* adn = (l < LL - 1) ? adt + (size_t)(l + 1) * RR * D : nullptr;
    const float* sin_ = (l & 1) ? ssrcB : ssrcA;
    const float* din_ = (l & 1) ? sdstB : sdstA;
    float* sou_ = (l & 1) ? ssrcA : ssrcB;
    float* dou_ = (l & 1) ? sdstA : sdstB;
    agg_fused_k<<<NN, 256, 0, stream>>>(csr, off, et, es, sin_, din_, hr2,
                                        hh, hl, wan, adn, sou_, dou_);
  }

  // [q|k] = h @ (W{q,k}·W1)^T + (W{q,k}·b1 + b{q,k})   — one GEMM, N=512
  gemm_split<64, 64, false, true><<<dim3(8, 64), 256, 0, stream>>>(
      hh, hl, fqkh, fqkl, bqk, nullptr, qkh, qkl, NN, 512, D);

  attn_mfma_k<<<dim3(64, BB * HH), 256, 0, stream>>>(qkh, qkl, out);
}

// Round 7
// 242.518 us; speedup vs baseline: 1.6433x; 1.0294x over previous
//
#include <hip/hip_runtime.h>
#include <math.h>

#define NN 4096      // nodes = B*S
#define D 256        // DIN == DOUT
#define RR 8
#define LL 4
#define EE 65536
#define BB 8
#define SS 512
#define HH 8

typedef short bf16x8 __attribute__((ext_vector_type(8)));
typedef float f32x4 __attribute__((ext_vector_type(4)));

__device__ __forceinline__ unsigned short f2bf(float f) {
  unsigned u = __float_as_uint(f);
  unsigned r = (u + 0x7fffu + ((u >> 16) & 1u)) >> 16;
  return (unsigned short)r;
}
__device__ __forceinline__ float bf2f(unsigned short s) {
  return __uint_as_float(((unsigned)s) << 16);
}

__device__ __forceinline__ void gload16(unsigned short* dst, const unsigned short* src) {
  __builtin_amdgcn_global_load_lds(
      (const __attribute__((address_space(1))) void*)src,
      (__attribute__((address_space(3))) void*)dst, 16, 0, 0);
}

// ---------------- split-bf16 MFMA GEMM ----------------
// C[M,N] = (Ah+Al)[M,K] * (Bh+Bl)[N,K]^T (+bias), fp32 accum.
// 3-term split: Ah*Bh + Al*Bh + Ah*Bl. 256 threads = 4 waves (2x2).
// Double-buffered LDS, ONE barrier per K-step (barrier's implicit vmcnt(0)
// drain publishes the staged tile). k-slot XOR-swizzle on BOTH global source
// (LDS dest linear, rule #21) and ds_read: 8-way conflict -> free 2-way.
template<int BM, int BN, bool F32OUT, bool SPLITOUT>
__global__ __launch_bounds__(256) void gemm_split(
    const unsigned short* __restrict__ Ah, const unsigned short* __restrict__ Al,
    const unsigned short* __restrict__ Bh, const unsigned short* __restrict__ Bl,
    const float* __restrict__ bias,
    float* __restrict__ C, unsigned short* __restrict__ Ch, unsigned short* __restrict__ Cl,
    int M, int N, int K)
{
  constexpr int MF = BM / 32;
  constexpr int NF = BN / 32;
  constexpr int ABUF = BM * 32;
  constexpr int BBUF = BN * 32;
  constexpr int BUFSZ = 2 * ABUF + 2 * BBUF;
  __shared__ unsigned short lds[2 * BUFSZ];

  const int t = threadIdx.x;
  const int lane = t & 63;
  const int w = t >> 6;
  const int wm = w >> 1, wn = w & 1;
  const int rb = blockIdx.y * BM;
  const int cb = blockIdx.x * BN;

  f32x4 acc[MF][NF];
#pragma unroll
  for (int m = 0; m < MF; ++m)
#pragma unroll
    for (int n = 0; n < NF; ++n)
      acc[m][n] = (f32x4){0.f, 0.f, 0.f, 0.f};

  const int srow = t >> 2;
  const int lslot = (t & 3) ^ ((srow >> 1) & 3);    // pre-swizzled source slot
  const unsigned short* gAh = Ah + (size_t)(rb + srow) * K + lslot * 8;
  const unsigned short* gAl = Al + (size_t)(rb + srow) * K + lslot * 8;
  const unsigned short* gBh = Bh + (size_t)(cb + srow) * K + lslot * 8;
  const unsigned short* gBl = Bl + (size_t)(cb + srow) * K + lslot * 8;

  auto stage = [&](int buf, int k0) {
    unsigned short* p = lds + buf * BUFSZ;
#pragma unroll
    for (int i = 0; i < BM / 64; ++i) {
      gload16(p + i * 2048 + t * 8,        gAh + (size_t)i * 64 * K + k0);
      gload16(p + ABUF + i * 2048 + t * 8, gAl + (size_t)i * 64 * K + k0);
    }
#pragma unroll
    for (int i = 0; i < BN / 64; ++i) {
      gload16(p + 2 * ABUF + i * 2048 + t * 8,        gBh + (size_t)i * 64 * K + k0);
      gload16(p + 2 * ABUF + BBUF + i * 2048 + t * 8, gBl + (size_t)i * 64 * K + k0);
    }
  };

  stage(0, 0);
  int cur = 0;
  for (int k0 = 0; k0 < K; k0 += 32) {
    __syncthreads();                         // drains vmcnt(0): tile visible
    if (k0 + 32 < K) stage(cur ^ 1, k0 + 32);  // prefetch overlaps compute
    const unsigned short* p = lds + cur * BUFSZ;

    bf16x8 ah[MF], al[MF];
#pragma unroll
    for (int m = 0; m < MF; ++m) {
      int row = wm * (BM / 2) + m * 16 + (lane & 15);
      int off = row * 32 + (((lane >> 4) ^ ((row >> 1) & 3)) << 3);
      ah[m] = *(const bf16x8*)(p + off);
      al[m] = *(const bf16x8*)(p + ABUF + off);
    }
#pragma unroll
    for (int n = 0; n < NF; ++n) {
      int brow = wn * (BN / 2) + n * 16 + (lane & 15);
      int boff = brow * 32 + (((lane >> 4) ^ ((brow >> 1) & 3)) << 3);
      bf16x8 bh = *(const bf16x8*)(p + 2 * ABUF + boff);
      bf16x8 bl = *(const bf16x8*)(p + 2 * ABUF + BBUF + boff);
#pragma unroll
      for (int m = 0; m < MF; ++m) {
        acc[m][n] = __builtin_amdgcn_mfma_f32_16x16x32_bf16(ah[m], bh, acc[m][n], 0, 0, 0);
        acc[m][n] = __builtin_amdgcn_mfma_f32_16x16x32_bf16(al[m], bh, acc[m][n], 0, 0, 0);
        acc[m][n] = __builtin_amdgcn_mfma_f32_16x16x32_bf16(ah[m], bl, acc[m][n], 0, 0, 0);
      }
    }
    cur ^= 1;
  }

#pragma unroll
  for (int m = 0; m < MF; ++m) {
#pragma unroll
    for (int n = 0; n < NF; ++n) {
      int row0 = rb + wm * (BM / 2) + m * 16 + (lane >> 4) * 4;
      int col = cb + wn * (BN / 2) + n * 16 + (lane & 15);
      float bv = bias ? bias[col] : 0.f;
#pragma unroll
      for (int j = 0; j < 4; ++j) {
        float v = acc[m][n][j] + bv;
        size_t idx = (size_t)(row0 + j) * N + col;
        if (F32OUT) C[idx] = v;
        if (SPLITOUT) {
          unsigned short hb = f2bf(v);
          Ch[idx] = hb;
          Cl[idx] = f2bf(v - bf2f(hb));
        }
      }
    }
  }
}

// -------- fused fp32 -> bf16 hi/lo split for x (first 1024 blocks) and Wl ----
__global__ __launch_bounds__(256) void cvt2_k(const float* __restrict__ x,
    unsigned short* __restrict__ xh, unsigned short* __restrict__ xl,
    const float* __restrict__ Wl,
    unsigned short* __restrict__ wlh, unsigned short* __restrict__ wll)
{
  const float* src; unsigned short* hi; unsigned short* lo; int i;
  if (blockIdx.x < 1024) { src = x;  hi = xh;  lo = xl;  i = blockIdx.x * 256 + threadIdx.x; }
  else                   { src = Wl; hi = wlh; lo = wll; i = (blockIdx.x - 1024) * 256 + threadIdx.x; }
  float4 v = ((const float4*)src)[i];
  ushort4 h, l;
  h.x = f2bf(v.x); l.x = f2bf(v.x - bf2f(h.x));
  h.y = f2bf(v.y); l.y = f2bf(v.y - bf2f(h.y));
  h.z = f2bf(v.z); l.z = f2bf(v.z - bf2f(h.z));
  h.w = f2bf(v.w); l.w = f2bf(v.w - bf2f(h.w));
  ((ushort4*)hi)[i] = h;
  ((ushort4*)lo)[i] = l;
}

// ---------------- Wgat [G][D][D] -> transposed hi/lo [G][D][D] (e-major) ---------
__global__ __launch_bounds__(256) void transp_split_k(const float* __restrict__ W,
    unsigned short* __restrict__ th, unsigned short* __restrict__ tl)
{
  __shared__ float s[32][33];
  int g = blockIdx.z, bi = blockIdx.y, bj = blockIdx.x;
  int t = threadIdx.x;
  int r = t >> 3, c = (t & 7) * 4;
  float4 v = *(const float4*)(W + ((size_t)g * D + bi * 32 + r) * D + bj * 32 + c);
  s[r][c + 0] = v.x; s[r][c + 1] = v.y; s[r][c + 2] = v.z; s[r][c + 3] = v.w;
  __syncthreads();
  size_t ob = ((size_t)g * D + bj * 32 + r) * D + bi * 32 + c;
  ushort4 h, l;
  float o0 = s[c + 0][r], o1 = s[c + 1][r], o2 = s[c + 2][r], o3 = s[c + 3][r];
  h.x = f2bf(o0); l.x = f2bf(o0 - bf2f(h.x));
  h.y = f2bf(o1); l.y = f2bf(o1 - bf2f(h.y));
  h.z = f2bf(o2); l.z = f2bf(o2 - bf2f(h.z));
  h.w = f2bf(o3); l.w = f2bf(o3 - bf2f(h.w));
  *(ushort4*)(th + ob) = h;
  *(ushort4*)(tl + ob) = l;
}

// ---------------- CSR build ----------------
__global__ void count_k(const int* __restrict__ ed, int* __restrict__ cnt) {
  int e = blockIdx.x * 256 + threadIdx.x;
  if (e < EE) atomicAdd(&cnt[ed[e]], 1);
}

__global__ __launch_bounds__(1024) void scan_k(const int* __restrict__ cnt,
    int* __restrict__ off, int* __restrict__ cur) {
  __shared__ int part[1024];
  int t = threadIdx.x;
  int base = t * 4;
  int c0 = cnt[base], c1 = cnt[base+1], c2 = cnt[base+2], c3 = cnt[base+3];
  int s = c0 + c1 + c2 + c3;
  part[t] = s;
  __syncthreads();
  for (int o = 1; o < 1024; o <<= 1) {
    int v = 0;
    if (t >= o) v = part[t - o];
    __syncthreads();
    part[t] += v;
    __syncthreads();
  }
  int excl = part[t] - s;
  off[base] = excl; off[base+1] = excl + c0; off[base+2] = excl + c0 + c1;
  off[base+3] = excl + c0 + c1 + c2;
  cur[base] = excl; cur[base+1] = excl + c0; cur[base+2] = excl + c0 + c1;
  cur[base+3] = excl + c0 + c1 + c2;
  if (t == 1023) off[NN] = EE;
}

__global__ void fill_k(const int* __restrict__ ed, int* __restrict__ cur,
                       int* __restrict__ csr) {
  int e = blockIdx.x * 256 + threadIdx.x;
  if (e < EE) { int p = atomicAdd(&cur[ed[e]], 1); csr[p] = e; }
}

// ------- wa[l,r,d] = sum_e Wgat[l,r,d,e] * a_src[l,r,e]  (all layers) -------
__global__ __launch_bounds__(256) void wa_all_k(const float* __restrict__ Wg,
    const float* __restrict__ asrc, float* __restrict__ wa)
{
  int wid = blockIdx.x * 4 + (threadIdx.x >> 6);
  int lane = threadIdx.x & 63;
  int lr = wid >> 8, d = wid & 255;
  const float* row = Wg + ((size_t)lr * D + d) * D;
  const float* av = asrc + (size_t)lr * D;
  float s = 0.f;
  for (int i = lane; i < D; i += 64) s += row[i] * av[i];
#pragma unroll
  for (int o = 32; o; o >>= 1) s += __shfl_down(s, o);
  if (lane == 0) wa[wid] = s;
}

// ------- fold: wqk1[i][k] = sum_j Wsel[i][j] * W1[j][k]  (i<256: Wq, else Wk) ----
__global__ __launch_bounds__(256) void fold_k(const float* __restrict__ Wq,
    const float* __restrict__ Wk, const float* __restrict__ W1,
    unsigned short* __restrict__ fh, unsigned short* __restrict__ fl)
{
  int j = (blockIdx.x & 3) * 64 + (threadIdx.x & 63);
  int i = (blockIdx.x >> 2) * 4 + (threadIdx.x >> 6);
  const float* row = i < 256 ? Wq + (size_t)i * D : Wk + (size_t)(i - 256) * D;
  float s = 0.f;
  for (int k = 0; k < D; ++k) s += row[k] * W1[(size_t)k * D + j];
  size_t idx = (size_t)i * D + j;
  unsigned short hb = f2bf(s);
  fh[idx] = hb;
  fl[idx] = f2bf(s - bf2f(hb));
}

// ------- fold bias: bqk[i] = Wsel[i] . b1 + bsel[i] ----------------
__global__ __launch_bounds__(256) void foldb_k(const float* __restrict__ Wq,
    const float* __restrict__ Wk, const float* __restrict__ b1,
    const float* __restrict__ bq, const float* __restrict__ bk,
    float* __restrict__ bqk)
{
  int idx = blockIdx.x * 4 + (threadIdx.x >> 6);
  int lane = threadIdx.x & 63;
  const float* row = idx < 256 ? Wq + (size_t)idx * D : Wk + (size_t)(idx - 256) * D;
  float s = 0.f;
  for (int i = lane; i < D; i += 64) s += row[i] * b1[i];
#pragma unroll
  for (int o = 32; o; o >>= 1) s += __shfl_down(s, o);
  if (lane == 0) bqk[idx] = s + (idx < 256 ? bq[idx] : bk[idx - 256]);
}

// ---- scores from split h: ssrc[r,n]=h[n].wa[r], sdst[r,n]=h[n].adst[r] ------
__global__ __launch_bounds__(256) void scores_split_k(
    const unsigned short* __restrict__ hh, const unsigned short* __restrict__ hl,
    const float* __restrict__ wa_l, const float* __restrict__ adst_l,
    float* __restrict__ ssrc, float* __restrict__ sdst)
{
  __shared__ float sh[256];
  int n = blockIdx.x, tid = threadIdx.x;
  size_t idx = (size_t)n * D + tid;
  sh[tid] = bf2f(hh[idx]) + bf2f(hl[idx]);
  __syncthreads();
  int wv = tid >> 6, lane = tid & 63;
#pragma unroll
  for (int rr = 0; rr < 2; ++rr) {
    int r = wv * 2 + rr;
    const float* wr = wa_l + (size_t)r * D;
    const float* ar = adst_l + (size_t)r * D;
    float s1 = sh[lane] * wr[lane] + sh[lane+64] * wr[lane+64]
             + sh[lane+128] * wr[lane+128] + sh[lane+192] * wr[lane+192];
    float s2 = sh[lane] * ar[lane] + sh[lane+64] * ar[lane+64]
             + sh[lane+128] * ar[lane+128] + sh[lane+192] * ar[lane+192];
#pragma unroll
    for (int o = 32; o; o >>= 1) { s1 += __shfl_down(s1, o); s2 += __shfl_down(s2, o); }
    if (lane == 0) { ssrc[(size_t)r * NN + n] = s1; sdst[(size_t)r * NN + n] = s2; }
  }
}

// ---- fully fused per-node: logits + softmax + WAVE-PARALLEL aggregate +
// ---- ELU + split + next-layer scores. One block (256 thr) per node.
__global__ __launch_bounds__(256) void agg_fused_k(
    const int* __restrict__ csr, const int* __restrict__ off,
    const int* __restrict__ et, const int* __restrict__ es,
    const float* __restrict__ ssrc, const float* __restrict__ sdst,
    const float* __restrict__ hr2,
    unsigned short* __restrict__ hh, unsigned short* __restrict__ hl,
    const float* __restrict__ wa_next, const float* __restrict__ adst_next,
    float* __restrict__ ssrc_o, float* __restrict__ sdst_o)
{
  __shared__ float slog[1024];
  __shared__ int soff[1024];
  __shared__ float sdn[RR];
  __shared__ float red[8];
  __shared__ float wred[4][256];
  int n = blockIdx.x, tid = threadIdx.x;
  int o0 = off[n];
  int deg = off[n + 1] - o0;
  if (deg > 1024) deg = 1024;
  if (tid < RR) sdn[tid] = sdst[(size_t)tid * NN + n];
  __syncthreads();
  // logits (leaky relu) into LDS
  for (int i = tid; i < deg; i += 256) {
    int e = csr[o0 + i];
    int t = et[e], s = es[e];
    float v = ssrc[(size_t)t * NN + s] + sdn[t];
    slog[i] = v > 0.f ? v : 0.2f * v;
    soff[i] = s * (RR * D) + t * D;
  }
  __syncthreads();
  int lane = tid & 63, wv = tid >> 6;
  // block max
  float lm = -INFINITY;
  for (int i = tid; i < deg; i += 256) lm = fmaxf(lm, slog[i]);
#pragma unroll
  for (int o = 32; o; o >>= 1) lm = fmaxf(lm, __shfl_xor(lm, o));
  if (lane == 0) red[wv] = lm;
  __syncthreads();
  float m = fmaxf(fmaxf(red[0], red[1]), fmaxf(red[2], red[3]));
  // exp + block sum
  float ls = 0.f;
  for (int i = tid; i < deg; i += 256) {
    float a = expf(slog[i] - m);
    slog[i] = a;
    ls += a;
  }
#pragma unroll
  for (int o = 32; o; o >>= 1) ls += __shfl_xor(ls, o);
  if (lane == 0) red[4 + wv] = ls;
  __syncthreads();            // publishes slog[] exp values + red sums
  float dinv = 1.f / (red[4] + red[5] + red[6] + red[7] + 1e-16f);
  // wave-parallel aggregation: wave wv takes edges i%4==wv; lane owns 4 chunks
  float a0 = 0.f, a1 = 0.f, a2 = 0.f, a3 = 0.f;
  for (int i = wv; i < deg; i += 4) {
    float al = slog[i];                       // LDS broadcast
    const float* row = hr2 + (size_t)soff[i];
    a0 += al * row[lane];
    a1 += al * row[lane + 64];
    a2 += al * row[lane + 128];
    a3 += al * row[lane + 192];
  }
  wred[wv][lane]       = a0;
  wred[wv][lane + 64]  = a1;
  wred[wv][lane + 128] = a2;
  wred[wv][lane + 192] = a3;
  __syncthreads();
  float acc = (wred[0][tid] + wred[1][tid]) + (wred[2][tid] + wred[3][tid]);
  acc *= dinv;
  float v = acc > 0.f ? acc : expm1f(acc);
  size_t idx = (size_t)n * D + tid;
  unsigned short hb = f2bf(v);
  hh[idx] = hb;
  hl[idx] = f2bf(v - bf2f(hb));

  if (wa_next) {   // fused scores for next layer (into ping-pong buffers)
    __syncthreads();
    slog[tid] = v;
    __syncthreads();
#pragma unroll
    for (int rr2 = 0; rr2 < 2; ++rr2) {
      int r = wv * 2 + rr2;
      const float* wr = wa_next + (size_t)r * D;
      const float* ar = adst_next + (size_t)r * D;
      float s1 = slog[lane] * wr[lane] + slog[lane+64] * wr[lane+64]
               + slog[lane+128] * wr[lane+128] + slog[lane+192] * wr[lane+192];
      float s2 = slog[lane] * ar[lane] + slog[lane+64] * ar[lane+64]
               + slog[lane+128] * ar[lane+128] + slog[lane+192] * ar[lane+192];
#pragma unroll
      for (int o = 32; o; o >>= 1) { s1 += __shfl_down(s1, o); s2 += __shfl_down(s2, o); }
      if (lane == 0) { ssrc_o[(size_t)r * NN + n] = s1; sdst_o[(size_t)r * NN + n] = s2; }
    }
  }
}

// ---------------- final attention scores via split-bf16 MFMA ----------------
// qk layout: [NN][512] hi/lo; q = cols [0,256), k = cols [256,512)
__global__ __launch_bounds__(256) void attn_mfma_k(
    const unsigned short* __restrict__ qkh, const unsigned short* __restrict__ qkl,
    float* __restrict__ out)
{
  int bh = blockIdx.y; int b = bh >> 3, hd = bh & 7;
  int rb = (blockIdx.x >> 3) * 64, cb = (blockIdx.x & 7) * 64;
  int t = threadIdx.x, lane = t & 63, w = t >> 6;
  int wm = w >> 1, wn = w & 1;
  int colq = hd * 32 + (lane >> 4) * 8;
  int colk = 256 + colq;
  int arow = b * SS + rb + wm * 32 + (lane & 15);
  int brow = b * SS + cb + wn * 32 + (lane & 15);

  bf16x8 aH[2], aL[2], bH[2], bL[2];
#pragma unroll
  for (int m = 0; m < 2; ++m) {
    size_t o1 = (size_t)(arow + m * 16) * 512 + colq;
    aH[m] = *(const bf16x8*)(qkh + o1);
    aL[m] = *(const bf16x8*)(qkl + o1);
    size_t o2 = (size_t)(brow + m * 16) * 512 + colk;
    bH[m] = *(const bf16x8*)(qkh + o2);
    bL[m] = *(const bf16x8*)(qkl + o2);
  }
  f32x4 acc[2][2];
#pragma unroll
  for (int m = 0; m < 2; ++m)
#pragma unroll
    for (int n = 0; n < 2; ++n) {
      acc[m][n] = (f32x4){0.f, 0.f, 0.f, 0.f};
      acc[m][n] = __builtin_amdgcn_mfma_f32_16x16x32_bf16(aH[m], bH[n], acc[m][n], 0, 0, 0);
      acc[m][n] = __builtin_amdgcn_mfma_f32_16x16x32_bf16(aL[m], bH[n], acc[m][n], 0, 0, 0);
      acc[m][n] = __builtin_amdgcn_mfma_f32_16x16x32_bf16(aH[m], bL[n], acc[m][n], 0, 0, 0);
    }
  const float scale = 0.17677669529663687f; // 1/sqrt(32)
  size_t ob = (size_t)bh * SS * SS;
#pragma unroll
  for (int m = 0; m < 2; ++m)
#pragma unroll
    for (int n = 0; n < 2; ++n) {
      int row0 = rb + wm * 32 + m * 16 + (lane >> 4) * 4;
      int col = cb + wn * 32 + n * 16 + (lane & 15);
#pragma unroll
      for (int j = 0; j < 4; ++j)
        out[ob + (size_t)(row0 + j) * SS + col] = acc[m][n][j] * scale;
    }
}

// ---------------- launcher ----------------
extern "C" void kernel_launch(void* const* d_in, const int* in_sizes, int n_in,
                              void* d_out, int out_size, void* d_ws, size_t ws_size,
                              hipStream_t stream) {
  const float* x    = (const float*)d_in[0];
  const int*   es   = (const int*)d_in[1];
  const int*   ed   = (const int*)d_in[2];
  const int*   et   = (const int*)d_in[3];
  const float* Wl   = (const float*)d_in[4];
  const float* bl   = (const float*)d_in[5];
  const float* Wgat = (const float*)d_in[6];
  const float* asr  = (const float*)d_in[7];
  const float* adt  = (const float*)d_in[8];
  const float* W1   = (const float*)d_in[9];
  const float* b1   = (const float*)d_in[10];
  const float* Wq   = (const float*)d_in[11];
  const float* bq   = (const float*)d_in[12];
  const float* Wk   = (const float*)d_in[13];
  const float* bk   = (const float*)d_in[14];
  float* out = (float*)d_out;

  char* w = (char*)d_ws;
  size_t o = 0;
  auto alloc = [&](size_t bytes) { void* p = w + o; o += (bytes + 255) & ~(size_t)255; return p; };
  unsigned short* hh    = (unsigned short*)alloc((size_t)NN * D * 2);
  unsigned short* hl    = (unsigned short*)alloc((size_t)NN * D * 2);
  unsigned short* Wgt_h = (unsigned short*)alloc((size_t)LL * RR * D * D * 2);
  unsigned short* Wgt_l = (unsigned short*)alloc((size_t)LL * RR * D * D * 2);
  unsigned short* wlh   = (unsigned short*)alloc((size_t)D * D * 2);
  unsigned short* wll   = (unsigned short*)alloc((size_t)D * D * 2);
  unsigned short* fqkh  = (unsigned short*)alloc((size_t)2 * D * D * 2);   // folded [512][256]
  unsigned short* fqkl  = (unsigned short*)alloc((size_t)2 * D * D * 2);
  float* bqk   = (float*)alloc((size_t)2 * D * 4);
  float* wa    = (float*)alloc((size_t)LL * RR * D * 4);
  float* ssrcA = (float*)alloc((size_t)RR * NN * 4);
  float* sdstA = (float*)alloc((size_t)RR * NN * 4);
  float* ssrcB = (float*)alloc((size_t)RR * NN * 4);
  float* sdstB = (float*)alloc((size_t)RR * NN * 4);
  int*   cnt   = (int*)alloc((size_t)NN * 4);
  int*   off   = (int*)alloc((size_t)(NN + 1) * 4);
  int*   cur   = (int*)alloc((size_t)NN * 4);
  int*   csr   = (int*)alloc((size_t)EE * 4);
  // 32 MB multipurpose region
  char* big = (char*)alloc((size_t)NN * RR * D * 4);
  float*          hr2 = (float*)big;                     // [NN][R*D] during layers
  unsigned short* xh  = (unsigned short*)big;            // before layers
  unsigned short* xl  = (unsigned short*)(big + (size_t)NN * D * 2);
  unsigned short* qkh = (unsigned short*)big;            // after layers [NN][512]
  unsigned short* qkl = (unsigned short*)(big + (size_t)NN * 512 * 2);

  // CSR build
  hipMemsetAsync(cnt, 0, NN * sizeof(int), stream);
  count_k<<<EE / 256, 256, 0, stream>>>(ed, cnt);
  scan_k<<<1, 1024, 0, stream>>>(cnt, off, cur);
  fill_k<<<EE / 256, 256, 0, stream>>>(ed, cur, csr);

  // conversions + precomputation
  cvt2_k<<<1024 + 64, 256, 0, stream>>>(x, xh, xl, Wl, wlh, wll);
  transp_split_k<<<dim3(8, 8, LL * RR), 256, 0, stream>>>(Wgat, Wgt_h, Wgt_l);
  wa_all_k<<<LL * RR * D / 4, 256, 0, stream>>>(Wgat, asr, wa);
  fold_k<<<512, 256, 0, stream>>>(Wq, Wk, W1, fqkh, fqkl);
  foldb_k<<<128, 256, 0, stream>>>(Wq, Wk, b1, bq, bk, bqk);

  // h = x @ Wl^T + bl (split out only)
  gemm_split<64, 64, false, true><<<dim3(4, 64), 256, 0, stream>>>(
      xh, xl, wlh, wll, bl, nullptr, hh, hl, NN, D, D);
  scores_split_k<<<NN, 256, 0, stream>>>(hh, hl, wa, adt, ssrcA, sdstA);

  for (int l = 0; l < LL; ++l) {
    // hr2[n, r*D+e] = h @ Wgat[l] (fused over relations, N=2048)
    gemm_split<128, 128, true, false><<<dim3(16, 32), 256, 0, stream>>>(
        hh, hl, Wgt_h + (size_t)l * RR * D * D, Wgt_l + (size_t)l * RR * D * D,
        nullptr, hr2, nullptr, nullptr, NN, RR * D, D);
    const float* wan = (l < LL - 1) ? wa + (size_t)(l + 1) * RR * D : nullptr;
    const float* adn = (l < LL - 1) ? adt + (size_t)(l + 1) * RR * D : nullptr;
    const float* sin_ = (l & 1) ? ssrcB : ssrcA;
    const float* din_ = (l & 1) ? sdstB : sdstA;
    float* sou_ = (l & 1) ? ssrcA : ssrcB;
    float* dou_ = (l & 1) ? sdstA : sdstB;
    agg_fused_k<<<NN, 256, 0, stream>>>(csr, off, et, es, sin_, din_, hr2,
                                        hh, hl, wan, adn, sou_, dou_);
  }

  // [q|k] = h @ (W{q,k}·W1)^T + (W{q,k}·b1 + b{q,k})   — one GEMM, N=512
  gemm_split<64, 64, false, true><<<dim3(8, 64), 256, 0, stream>>>(
      hh, hl, fqkh, fqkl, bqk, nullptr, qkh, qkl, NN, 512, D);

  attn_mfma_k<<<dim3(64, BB * HH), 256, 0, stream>>>(qkh, qkl, out);
}

// Round 9
// 226.331 us; speedup vs baseline: 1.7608x; 1.0715x over previous
//
#include <hip/hip_runtime.h>
#include <math.h>

#define NN 4096      // nodes = B*S
#define D 256        // DIN == DOUT
#define RR 8
#define LL 4
#define EE 65536
#define BB 8
#define SS 512
#define HH 8
#define RK 256       // RGAT GEMM K
#define RN 2048      // RGAT GEMM N (R*D)

typedef short bf16x8 __attribute__((ext_vector_type(8)));
typedef float f32x4 __attribute__((ext_vector_type(4)));

__device__ __forceinline__ unsigned short f2bf(float f) {
  unsigned u = __float_as_uint(f);
  unsigned r = (u + 0x7fffu + ((u >> 16) & 1u)) >> 16;
  return (unsigned short)r;
}
__device__ __forceinline__ float bf2f(unsigned short s) {
  return __uint_as_float(((unsigned)s) << 16);
}

__device__ __forceinline__ void gload16(unsigned short* dst, const unsigned short* src) {
  __builtin_amdgcn_global_load_lds(
      (const __attribute__((address_space(1))) void*)src,
      (__attribute__((address_space(3))) void*)dst, 16, 0, 0);
}

// ---------------- split-bf16 MFMA GEMM (64x64 tile, 4 waves) ----------------
// C[M,N] = (Ah+Al)[M,K] * (Bh+Bl)[N,K]^T (+bias), fp32 accum, 3-term split.
// Double-buffered LDS, 1 barrier/K-step; k-slot XOR swizzle both sides.
template<int BM, int BN, bool F32OUT, bool SPLITOUT>
__global__ __launch_bounds__(256) void gemm_split(
    const unsigned short* __restrict__ Ah, const unsigned short* __restrict__ Al,
    const unsigned short* __restrict__ Bh, const unsigned short* __restrict__ Bl,
    const float* __restrict__ bias,
    float* __restrict__ C, unsigned short* __restrict__ Ch, unsigned short* __restrict__ Cl,
    int M, int N, int K)
{
  constexpr int MF = BM / 32;
  constexpr int NF = BN / 32;
  constexpr int ABUF = BM * 32;
  constexpr int BBUF = BN * 32;
  constexpr int BUFSZ = 2 * ABUF + 2 * BBUF;
  __shared__ unsigned short lds[2 * BUFSZ];

  const int t = threadIdx.x;
  const int lane = t & 63;
  const int w = t >> 6;
  const int wm = w >> 1, wn = w & 1;
  const int rb = blockIdx.y * BM;
  const int cb = blockIdx.x * BN;

  f32x4 acc[MF][NF];
#pragma unroll
  for (int m = 0; m < MF; ++m)
#pragma unroll
    for (int n = 0; n < NF; ++n)
      acc[m][n] = (f32x4){0.f, 0.f, 0.f, 0.f};

  const int srow = t >> 2;
  const int lslot = (t & 3) ^ ((srow >> 1) & 3);
  const unsigned short* gAh = Ah + (size_t)(rb + srow) * K + lslot * 8;
  const unsigned short* gAl = Al + (size_t)(rb + srow) * K + lslot * 8;
  const unsigned short* gBh = Bh + (size_t)(cb + srow) * K + lslot * 8;
  const unsigned short* gBl = Bl + (size_t)(cb + srow) * K + lslot * 8;

  auto stage = [&](int buf, int k0) {
    unsigned short* p = lds + buf * BUFSZ;
#pragma unroll
    for (int i = 0; i < BM / 64; ++i) {
      gload16(p + i * 2048 + t * 8,        gAh + (size_t)i * 64 * K + k0);
      gload16(p + ABUF + i * 2048 + t * 8, gAl + (size_t)i * 64 * K + k0);
    }
#pragma unroll
    for (int i = 0; i < BN / 64; ++i) {
      gload16(p + 2 * ABUF + i * 2048 + t * 8,        gBh + (size_t)i * 64 * K + k0);
      gload16(p + 2 * ABUF + BBUF + i * 2048 + t * 8, gBl + (size_t)i * 64 * K + k0);
    }
  };

  stage(0, 0);
  int cur = 0;
  for (int k0 = 0; k0 < K; k0 += 32) {
    __syncthreads();
    if (k0 + 32 < K) stage(cur ^ 1, k0 + 32);
    const unsigned short* p = lds + cur * BUFSZ;

    bf16x8 ah[MF], al[MF];
#pragma unroll
    for (int m = 0; m < MF; ++m) {
      int row = wm * (BM / 2) + m * 16 + (lane & 15);
      int off = row * 32 + (((lane >> 4) ^ ((row >> 1) & 3)) << 3);
      ah[m] = *(const bf16x8*)(p + off);
      al[m] = *(const bf16x8*)(p + ABUF + off);
    }
#pragma unroll
    for (int n = 0; n < NF; ++n) {
      int brow = wn * (BN / 2) + n * 16 + (lane & 15);
      int boff = brow * 32 + (((lane >> 4) ^ ((brow >> 1) & 3)) << 3);
      bf16x8 bh = *(const bf16x8*)(p + 2 * ABUF + boff);
      bf16x8 bl = *(const bf16x8*)(p + 2 * ABUF + BBUF + boff);
#pragma unroll
      for (int m = 0; m < MF; ++m) {
        acc[m][n] = __builtin_amdgcn_mfma_f32_16x16x32_bf16(ah[m], bh, acc[m][n], 0, 0, 0);
        acc[m][n] = __builtin_amdgcn_mfma_f32_16x16x32_bf16(al[m], bh, acc[m][n], 0, 0, 0);
        acc[m][n] = __builtin_amdgcn_mfma_f32_16x16x32_bf16(ah[m], bl, acc[m][n], 0, 0, 0);
      }
    }
    cur ^= 1;
  }

#pragma unroll
  for (int m = 0; m < MF; ++m) {
#pragma unroll
    for (int n = 0; n < NF; ++n) {
      int row0 = rb + wm * (BM / 2) + m * 16 + (lane >> 4) * 4;
      int col = cb + wn * (BN / 2) + n * 16 + (lane & 15);
      float bv = bias ? bias[col] : 0.f;
#pragma unroll
      for (int j = 0; j < 4; ++j) {
        float v = acc[m][n][j] + bv;
        size_t idx = (size_t)(row0 + j) * N + col;
        if (F32OUT) C[idx] = v;
        if (SPLITOUT) {
          unsigned short hb = f2bf(v);
          Ch[idx] = hb;
          Cl[idx] = f2bf(v - bf2f(hb));
        }
      }
    }
  }
}

// ------- RGAT GEMM: 128x128 tile, 128 thr = 2 waves, wave tile 64x128 --------
// Same dbuf + swizzle scheme; FLOP/LDS-byte 48 -> 64 (compute-bound).
// M=NN, N=RN=2048, K=RK=256, fp32 out, no bias.
__global__ __launch_bounds__(128, 1) void gemm_rgat(
    const unsigned short* __restrict__ Ah, const unsigned short* __restrict__ Al,
    const unsigned short* __restrict__ Bh, const unsigned short* __restrict__ Bl,
    float* __restrict__ C)
{
  constexpr int ABUF = 128 * 32;             // 4096 shorts per half-tile
  constexpr int BUFSZ = 4 * ABUF;            // Ah,Al,Bh,Bl
  __shared__ unsigned short lds[2 * BUFSZ];  // 64 KB

  const int t = threadIdx.x;                 // 0..127
  const int lane = t & 63;
  const int wm = t >> 6;                     // wave -> 64-row half
  const int rb = blockIdx.y * 128;
  const int cb = blockIdx.x * 128;

  f32x4 acc[4][8];
#pragma unroll
  for (int m = 0; m < 4; ++m)
#pragma unroll
    for (int n = 0; n < 8; ++n)
      acc[m][n] = (f32x4){0.f, 0.f, 0.f, 0.f};

  const int srow = t >> 2;                   // 0..31
  const int lslot = (t & 3) ^ ((srow >> 1) & 3);
  const unsigned short* gAh = Ah + (size_t)(rb + srow) * RK + lslot * 8;
  const unsigned short* gAl = Al + (size_t)(rb + srow) * RK + lslot * 8;
  const unsigned short* gBh = Bh + (size_t)(cb + srow) * RK + lslot * 8;
  const unsigned short* gBl = Bl + (size_t)(cb + srow) * RK + lslot * 8;

  auto stage = [&](int buf, int k0) {
    unsigned short* p = lds + buf * BUFSZ;
#pragma unroll
    for (int i = 0; i < 4; ++i) {
      gload16(p + i * 1024 + t * 8,            gAh + (size_t)i * 32 * RK + k0);
      gload16(p + ABUF + i * 1024 + t * 8,     gAl + (size_t)i * 32 * RK + k0);
      gload16(p + 2 * ABUF + i * 1024 + t * 8, gBh + (size_t)i * 32 * RK + k0);
      gload16(p + 3 * ABUF + i * 1024 + t * 8, gBl + (size_t)i * 32 * RK + k0);
    }
  };

  stage(0, 0);
  int cur = 0;
  for (int k0 = 0; k0 < RK; k0 += 32) {
    __syncthreads();                          // vmcnt(0) drain: tile visible
    if (k0 + 32 < RK) stage(cur ^ 1, k0 + 32);
    const unsigned short* p = lds + cur * BUFSZ;

    bf16x8 ah[4], al[4];
#pragma unroll
    for (int m = 0; m < 4; ++m) {
      int row = wm * 64 + m * 16 + (lane & 15);
      int off = row * 32 + (((lane >> 4) ^ ((row >> 1) & 3)) << 3);
      ah[m] = *(const bf16x8*)(p + off);
      al[m] = *(const bf16x8*)(p + ABUF + off);
    }
#pragma unroll
    for (int n = 0; n < 8; ++n) {
      int brow = n * 16 + (lane & 15);
      int boff = brow * 32 + (((lane >> 4) ^ ((brow >> 1) & 3)) << 3);
      bf16x8 bh = *(const bf16x8*)(p + 2 * ABUF + boff);
      bf16x8 bl = *(const bf16x8*)(p + 3 * ABUF + boff);
#pragma unroll
      for (int m = 0; m < 4; ++m) {
        acc[m][n] = __builtin_amdgcn_mfma_f32_16x16x32_bf16(ah[m], bh, acc[m][n], 0, 0, 0);
        acc[m][n] = __builtin_amdgcn_mfma_f32_16x16x32_bf16(al[m], bh, acc[m][n], 0, 0, 0);
        acc[m][n] = __builtin_amdgcn_mfma_f32_16x16x32_bf16(ah[m], bl, acc[m][n], 0, 0, 0);
      }
    }
    cur ^= 1;
  }

#pragma unroll
  for (int m = 0; m < 4; ++m) {
#pragma unroll
    for (int n = 0; n < 8; ++n) {
      int row0 = rb + wm * 64 + m * 16 + (lane >> 4) * 4;
      int col = cb + n * 16 + (lane & 15);
#pragma unroll
      for (int j = 0; j < 4; ++j)
        C[(size_t)(row0 + j) * RN + col] = acc[m][n][j];
    }
  }
}

// ---------------- CSR build ----------------
__global__ void count_k(const int* __restrict__ ed, int* __restrict__ cnt,
                        float* __restrict__ wa) {
  if (blockIdx.x < 32) wa[blockIdx.x * 256 + threadIdx.x] = 0.f;   // zero wa
  int e = blockIdx.x * 256 + threadIdx.x;
  if (e < EE) atomicAdd(&cnt[ed[e]], 1);
}

__global__ __launch_bounds__(1024) void scan_k(const int* __restrict__ cnt,
    int* __restrict__ off, int* __restrict__ cur) {
  __shared__ int part[1024];
  int t = threadIdx.x;
  int base = t * 4;
  int c0 = cnt[base], c1 = cnt[base+1], c2 = cnt[base+2], c3 = cnt[base+3];
  int s = c0 + c1 + c2 + c3;
  part[t] = s;
  __syncthreads();
  for (int o = 1; o < 1024; o <<= 1) {
    int v = 0;
    if (t >= o) v = part[t - o];
    __syncthreads();
    part[t] += v;
    __syncthreads();
  }
  int excl = part[t] - s;
  off[base] = excl; off[base+1] = excl + c0; off[base+2] = excl + c0 + c1;
  off[base+3] = excl + c0 + c1 + c2;
  cur[base] = excl; cur[base+1] = excl + c0; cur[base+2] = excl + c0 + c1;
  cur[base+3] = excl + c0 + c1 + c2;
  if (t == 1023) off[NN] = EE;
}

__global__ void fill_k(const int* __restrict__ ed, int* __restrict__ cur,
                       int* __restrict__ csr) {
  int e = blockIdx.x * 256 + threadIdx.x;
  if (e < EE) { int p = atomicAdd(&cur[ed[e]], 1); csr[p] = e; }
}

// ---------------- mega prep: cvt(x,Wl) + fold + foldb + transp+wa ------------
// blocks [0,1024): x split; [1024,1088): Wl split; [1088,1600): fold Wq/Wk*W1;
// [1600,1728): fold bias; [1728,3776): Wgat transpose-split (g=0..31) + wa dots.
__global__ __launch_bounds__(256) void prep_k(
    const float* __restrict__ x, unsigned short* __restrict__ xh, unsigned short* __restrict__ xl,
    const float* __restrict__ Wl, unsigned short* __restrict__ wlh, unsigned short* __restrict__ wll,
    const float* __restrict__ Wq, const float* __restrict__ Wk, const float* __restrict__ W1,
    unsigned short* __restrict__ fqkh, unsigned short* __restrict__ fqkl,
    const float* __restrict__ b1, const float* __restrict__ bq, const float* __restrict__ bk,
    float* __restrict__ bqk,
    const float* __restrict__ Wgat, const float* __restrict__ asrc,
    unsigned short* __restrict__ th, unsigned short* __restrict__ tl,
    float* __restrict__ wa)
{
  __shared__ float s[32][33];
  int b = blockIdx.x, t = threadIdx.x;
  if (b < 1088) {
    const float* src; unsigned short* hi; unsigned short* lo; int i;
    if (b < 1024) { src = x;  hi = xh;  lo = xl;  i = b * 256 + t; }
    else          { src = Wl; hi = wlh; lo = wll; i = (b - 1024) * 256 + t; }
    float4 v = ((const float4*)src)[i];
    ushort4 h, l;
    h.x = f2bf(v.x); l.x = f2bf(v.x - bf2f(h.x));
    h.y = f2bf(v.y); l.y = f2bf(v.y - bf2f(h.y));
    h.z = f2bf(v.z); l.z = f2bf(v.z - bf2f(h.z));
    h.w = f2bf(v.w); l.w = f2bf(v.w - bf2f(h.w));
    ((ushort4*)hi)[i] = h;
    ((ushort4*)lo)[i] = l;
  } else if (b < 1600) {
    int b2 = b - 1088;
    int j = (b2 & 3) * 64 + (t & 63);
    int i = (b2 >> 2) * 4 + (t >> 6);
    const float* row = i < 256 ? Wq + (size_t)i * D : Wk + (size_t)(i - 256) * D;
    float sm = 0.f;
    for (int k = 0; k < D; ++k) sm += row[k] * W1[(size_t)k * D + j];
    size_t idx = (size_t)i * D + j;
    unsigned short hb = f2bf(sm);
    fqkh[idx] = hb;
    fqkl[idx] = f2bf(sm - bf2f(hb));
  } else if (b < 1728) {
    int b2 = b - 1600;
    int idx = b2 * 4 + (t >> 6);
    int lane = t & 63;
    const float* row = idx < 256 ? Wq + (size_t)idx * D : Wk + (size_t)(idx - 256) * D;
    float sm = 0.f;
    for (int i = lane; i < D; i += 64) sm += row[i] * b1[i];
#pragma unroll
    for (int o = 32; o; o >>= 1) sm += __shfl_down(sm, o);
    if (lane == 0) bqk[idx] = sm + (idx < 256 ? bq[idx] : bk[idx - 256]);
  } else {
    int b2 = b - 1728;                 // 0..2047: g = l*8+r in [0,32)
    int g = b2 >> 6, bi = (b2 >> 3) & 7, bj = b2 & 7;
    int r = t >> 3, c = (t & 7) * 4;
    float4 v = *(const float4*)(Wgat + ((size_t)g * D + bi * 32 + r) * D + bj * 32 + c);
    s[r][c + 0] = v.x; s[r][c + 1] = v.y; s[r][c + 2] = v.z; s[r][c + 3] = v.w;
    __syncthreads();
    size_t ob = ((size_t)g * D + bj * 32 + r) * D + bi * 32 + c;
    ushort4 h, l4;
    float o0 = s[c + 0][r], o1 = s[c + 1][r], o2 = s[c + 2][r], o3 = s[c + 3][r];
    h.x = f2bf(o0); l4.x = f2bf(o0 - bf2f(h.x));
    h.y = f2bf(o1); l4.y = f2bf(o1 - bf2f(h.y));
    h.z = f2bf(o2); l4.z = f2bf(o2 - bf2f(h.z));
    h.w = f2bf(o3); l4.w = f2bf(o3 - bf2f(h.w));
    *(ushort4*)(th + ob) = h;
    *(ushort4*)(tl + ob) = l4;
    // wa[g, bi*32+t] += sum_c W[d][e]*a[e] over this e-tile
    if (t < 32) {
      const float* av = asrc + (size_t)g * D + bj * 32;
      float p2 = 0.f;
#pragma unroll
      for (int cc = 0; cc < 32; ++cc) p2 += s[t][cc] * av[cc];
      atomicAdd(&wa[(size_t)g * D + bi * 32 + t], p2);
    }
  }
}

// ---- scores from split h: ssrc[r,n]=h[n].wa[r], sdst[r,n]=h[n].adst[r] ------
__global__ __launch_bounds__(256) void scores_split_k(
    const unsigned short* __restrict__ hh, const unsigned short* __restrict__ hl,
    const float* __restrict__ wa_l, const float* __restrict__ adst_l,
    float* __restrict__ ssrc, float* __restrict__ sdst)
{
  __shared__ float sh[256];
  int n = blockIdx.x, tid = threadIdx.x;
  size_t idx = (size_t)n * D + tid;
  sh[tid] = bf2f(hh[idx]) + bf2f(hl[idx]);
  __syncthreads();
  int wv = tid >> 6, lane = tid & 63;
#pragma unroll
  for (int rr = 0; rr < 2; ++rr) {
    int r = wv * 2 + rr;
    const float* wr = wa_l + (size_t)r * D;
    const float* ar = adst_l + (size_t)r * D;
    float s1 = sh[lane] * wr[lane] + sh[lane+64] * wr[lane+64]
             + sh[lane+128] * wr[lane+128] + sh[lane+192] * wr[lane+192];
    float s2 = sh[lane] * ar[lane] + sh[lane+64] * ar[lane+64]
             + sh[lane+128] * ar[lane+128] + sh[lane+192] * ar[lane+192];
#pragma unroll
    for (int o = 32; o; o >>= 1) { s1 += __shfl_down(s1, o); s2 += __shfl_down(s2, o); }
    if (lane == 0) { ssrc[(size_t)r * NN + n] = s1; sdst[(size_t)r * NN + n] = s2; }
  }
}

// ---- fused per-node: logits + softmax + wave-parallel float4 aggregate +
// ---- ELU + split + next-layer scores. One block (256 thr) per node.
__global__ __launch_bounds__(256) void agg_fused_k(
    const int* __restrict__ csr, const int* __restrict__ off,
    const int* __restrict__ et, const int* __restrict__ es,
    const float* __restrict__ ssrc, const float* __restrict__ sdst,
    const float* __restrict__ hr2,
    unsigned short* __restrict__ hh, unsigned short* __restrict__ hl,
    const float* __restrict__ wa_next, const float* __restrict__ adst_next,
    float* __restrict__ ssrc_o, float* __restrict__ sdst_o)
{
  __shared__ float slog[1024];
  __shared__ int soff[1024];
  __shared__ float sdn[RR];
  __shared__ float red[8];
  __shared__ float wred[4][256];
  int n = blockIdx.x, tid = threadIdx.x;
  int o0 = off[n];
  int deg = off[n + 1] - o0;
  if (deg > 1024) deg = 1024;
  if (tid < RR) sdn[tid] = sdst[(size_t)tid * NN + n];
  __syncthreads();
  for (int i = tid; i < deg; i += 256) {
    int e = csr[o0 + i];
    int t = et[e], s = es[e];
    float v = ssrc[(size_t)t * NN + s] + sdn[t];
    slog[i] = v > 0.f ? v : 0.2f * v;
    soff[i] = s * (RR * D) + t * D;
  }
  __syncthreads();
  int lane = tid & 63, wv = tid >> 6;
  float lm = -INFINITY;
  for (int i = tid; i < deg; i += 256) lm = fmaxf(lm, slog[i]);
#pragma unroll
  for (int o = 32; o; o >>= 1) lm = fmaxf(lm, __shfl_xor(lm, o));
  if (lane == 0) red[wv] = lm;
  __syncthreads();
  float m = fmaxf(fmaxf(red[0], red[1]), fmaxf(red[2], red[3]));
  float ls = 0.f;
  for (int i = tid; i < deg; i += 256) {
    float a = expf(slog[i] - m);
    slog[i] = a;
    ls += a;
  }
#pragma unroll
  for (int o = 32; o; o >>= 1) ls += __shfl_xor(ls, o);
  if (lane == 0) red[4 + wv] = ls;
  __syncthreads();
  float dinv = 1.f / (red[4] + red[5] + red[6] + red[7] + 1e-16f);
  // wave-parallel aggregation: wave wv takes edges i%4==wv; lane owns float4 chunk
  float4 a4 = make_float4(0.f, 0.f, 0.f, 0.f);
  for (int i = wv; i < deg; i += 4) {
    float al = slog[i];
    float4 rv = ((const float4*)(hr2 + (size_t)soff[i]))[lane];
    a4.x += al * rv.x; a4.y += al * rv.y; a4.z += al * rv.z; a4.w += al * rv.w;
  }
  ((float4*)wred[wv])[lane] = a4;
  __syncthreads();
  float acc = (wred[0][tid] + wred[1][tid]) + (wred[2][tid] + wred[3][tid]);
  acc *= dinv;
  float v = acc > 0.f ? acc : expm1f(acc);
  size_t idx = (size_t)n * D + tid;
  unsigned short hb = f2bf(v);
  hh[idx] = hb;
  hl[idx] = f2bf(v - bf2f(hb));

  if (wa_next) {
    __syncthreads();
    slog[tid] = v;
    __syncthreads();
#pragma unroll
    for (int rr2 = 0; rr2 < 2; ++rr2) {
      int r = wv * 2 + rr2;
      const float* wr = wa_next + (size_t)r * D;
      const float* ar = adst_next + (size_t)r * D;
      float s1 = slog[lane] * wr[lane] + slog[lane+64] * wr[lane+64]
               + slog[lane+128] * wr[lane+128] + slog[lane+192] * wr[lane+192];
      float s2 = slog[lane] * ar[lane] + slog[lane+64] * ar[lane+64]
               + slog[lane+128] * ar[lane+128] + slog[lane+192] * ar[lane+192];
#pragma unroll
      for (int o = 32; o; o >>= 1) { s1 += __shfl_down(s1, o); s2 += __shfl_down(s2, o); }
      if (lane == 0) { ssrc_o[(size_t)r * NN + n] = s1; sdst_o[(size_t)r * NN + n] = s2; }
    }
  }
}

// ---------------- final attention scores via split-bf16 MFMA ----------------
// qk layout: [NN][512] hi/lo; q = cols [0,256), k = cols [256,512)
__global__ __launch_bounds__(256) void attn_mfma_k(
    const unsigned short* __restrict__ qkh, const unsigned short* __restrict__ qkl,
    float* __restrict__ out)
{
  int bh = blockIdx.y; int b = bh >> 3, hd = bh & 7;
  int rb = (blockIdx.x >> 3) * 64, cb = (blockIdx.x & 7) * 64;
  int t = threadIdx.x, lane = t & 63, w = t >> 6;
  int wm = w >> 1, wn = w & 1;
  int colq = hd * 32 + (lane >> 4) * 8;
  int colk = 256 + colq;
  int arow = b * SS + rb + wm * 32 + (lane & 15);
  int brow = b * SS + cb + wn * 32 + (lane & 15);

  bf16x8 aH[2], aL[2], bH[2], bL[2];
#pragma unroll
  for (int m = 0; m < 2; ++m) {
    size_t o1 = (size_t)(arow + m * 16) * 512 + colq;
    aH[m] = *(const bf16x8*)(qkh + o1);
    aL[m] = *(const bf16x8*)(qkl + o1);
    size_t o2 = (size_t)(brow + m * 16) * 512 + colk;
    bH[m] = *(const bf16x8*)(qkh + o2);
    bL[m] = *(const bf16x8*)(qkl + o2);
  }
  f32x4 acc[2][2];
#pragma unroll
  for (int m = 0; m < 2; ++m)
#pragma unroll
    for (int n = 0; n < 2; ++n) {
      acc[m][n] = (f32x4){0.f, 0.f, 0.f, 0.f};
      acc[m][n] = __builtin_amdgcn_mfma_f32_16x16x32_bf16(aH[m], bH[n], acc[m][n], 0, 0, 0);
      acc[m][n] = __builtin_amdgcn_mfma_f32_16x16x32_bf16(aL[m], bH[n], acc[m][n], 0, 0, 0);
      acc[m][n] = __builtin_amdgcn_mfma_f32_16x16x32_bf16(aH[m], bL[n], acc[m][n], 0, 0, 0);
    }
  const float scale = 0.17677669529663687f; // 1/sqrt(32)
  size_t ob = (size_t)bh * SS * SS;
#pragma unroll
  for (int m = 0; m < 2; ++m)
#pragma unroll
    for (int n = 0; n < 2; ++n) {
      int row0 = rb + wm * 32 + m * 16 + (lane >> 4) * 4;
      int col = cb + wn * 32 + n * 16 + (lane & 15);
#pragma unroll
      for (int j = 0; j < 4; ++j)
        out[ob + (size_t)(row0 + j) * SS + col] = acc[m][n][j] * scale;
    }
}

// ---------------- launcher ----------------
extern "C" void kernel_launch(void* const* d_in, const int* in_sizes, int n_in,
                              void* d_out, int out_size, void* d_ws, size_t ws_size,
                              hipStream_t stream) {
  const float* x    = (const float*)d_in[0];
  const int*   es   = (const int*)d_in[1];
  const int*   ed   = (const int*)d_in[2];
  const int*   et   = (const int*)d_in[3];
  const float* Wl   = (const float*)d_in[4];
  const float* bl   = (const float*)d_in[5];
  const float* Wgat = (const float*)d_in[6];
  const float* asr  = (const float*)d_in[7];
  const float* adt  = (const float*)d_in[8];
  const float* W1   = (const float*)d_in[9];
  const float* b1   = (const float*)d_in[10];
  const float* Wq   = (const float*)d_in[11];
  const float* bq   = (const float*)d_in[12];
  const float* Wk   = (const float*)d_in[13];
  const float* bk   = (const float*)d_in[14];
  float* out = (float*)d_out;

  char* w = (char*)d_ws;
  size_t o = 0;
  auto alloc = [&](size_t bytes) { void* p = w + o; o += (bytes + 255) & ~(size_t)255; return p; };
  unsigned short* hh    = (unsigned short*)alloc((size_t)NN * D * 2);
  unsigned short* hl    = (unsigned short*)alloc((size_t)NN * D * 2);
  unsigned short* Wgt_h = (unsigned short*)alloc((size_t)LL * RR * D * D * 2);
  unsigned short* Wgt_l = (unsigned short*)alloc((size_t)LL * RR * D * D * 2);
  unsigned short* wlh   = (unsigned short*)alloc((size_t)D * D * 2);
  unsigned short* wll   = (unsigned short*)alloc((size_t)D * D * 2);
  unsigned short* fqkh  = (unsigned short*)alloc((size_t)2 * D * D * 2);   // folded [512][256]
  unsigned short* fqkl  = (unsigned short*)alloc((size_t)2 * D * D * 2);
  float* bqk   = (float*)alloc((size_t)2 * D * 4);
  float* wa    = (float*)alloc((size_t)LL * RR * D * 4);
  float* ssrcA = (float*)alloc((size_t)RR * NN * 4);
  float* sdstA = (float*)alloc((size_t)RR * NN * 4);
  float* ssrcB = (float*)alloc((size_t)RR * NN * 4);
  float* sdstB = (float*)alloc((size_t)RR * NN * 4);
  int*   cnt   = (int*)alloc((size_t)NN * 4);
  int*   off   = (int*)alloc((size_t)(NN + 1) * 4);
  int*   cur   = (int*)alloc((size_t)NN * 4);
  int*   csr   = (int*)alloc((size_t)EE * 4);
  // 32 MB multipurpose region
  char* big = (char*)alloc((size_t)NN * RR * D * 4);
  float*          hr2 = (float*)big;                     // [NN][R*D] during layers
  unsigned short* xh  = (unsigned short*)big;            // before layers
  unsigned short* xl  = (unsigned short*)(big + (size_t)NN * D * 2);
  unsigned short* qkh = (unsigned short*)big;            // after layers [NN][512]
  unsigned short* qkl = (unsigned short*)(big + (size_t)NN * 512 * 2);

  // CSR build (count_k also zeroes wa ahead of prep_k's atomics)
  hipMemsetAsync(cnt, 0, NN * sizeof(int), stream);
  count_k<<<EE / 256, 256, 0, stream>>>(ed, cnt, wa);
  scan_k<<<1, 1024, 0, stream>>>(cnt, off, cur);
  fill_k<<<EE / 256, 256, 0, stream>>>(ed, cur, csr);

  // one mega prep launch: cvt(x,Wl) + fold(WqW1,WkW1) + foldb + transp+wa
  // transpose phase needs LL*RR*8*8 = 2048 blocks (g in [0,32)) -> total 3776
  prep_k<<<3776, 256, 0, stream>>>(x, xh, xl, Wl, wlh, wll, Wq, Wk, W1,
                                   fqkh, fqkl, b1, bq, bk, bqk,
                                   Wgat, asr, Wgt_h, Wgt_l, wa);

  // h = x @ Wl^T + bl (split out only)
  gemm_split<64, 64, false, true><<<dim3(4, 64), 256, 0, stream>>>(
      xh, xl, wlh, wll, bl, nullptr, hh, hl, NN, D, D);
  scores_split_k<<<NN, 256, 0, stream>>>(hh, hl, wa, adt, ssrcA, sdstA);

  for (int l = 0; l < LL; ++l) {
    gemm_rgat<<<dim3(RN / 128, NN / 128), 128, 0, stream>>>(
        hh, hl, Wgt_h + (size_t)l * RR * D * D, Wgt_l + (size_t)l * RR * D * D, hr2);
    const float* wan = (l < LL - 1) ? wa + (size_t)(l + 1) * RR * D : nullptr;
    const float* adn = (l < LL - 1) ? adt + (size_t)(l + 1) * RR * D : nullptr;
    const float* sin_ = (l & 1) ? ssrcB : ssrcA;
    const float* din_ = (l & 1) ? sdstB : sdstA;
    float* sou_ = (l & 1) ? ssrcA : ssrcB;
    float* dou_ = (l & 1) ? sdstA : sdstB;
    agg_fused_k<<<NN, 256, 0, stream>>>(csr, off, et, es, sin_, din_, hr2,
                                        hh, hl, wan, adn, sou_, dou_);
  }

  // [q|k] = h @ (W{q,k}·W1)^T + (W{q,k}·b1 + b{q,k})   — one GEMM, N=512
  gemm_split<64, 64, false, true><<<dim3(8, 64), 256, 0, stream>>>(
      hh, hl, fqkh, fqkl, bqk, nullptr, qkh, qkl, NN, 512, D);

  attn_mfma_k<<<dim3(64, BB * HH), 256, 0, stream>>>(qkh, qkl, out);
}